// Round 4
// baseline (4731.460 us; speedup 1.0000x reference)
//
#include <hip/hip_runtime.h>

// InverseTransitionModel, B=32768, H=256, 10 GRU steps.
// v4: rollout = 256 blocks x 1024 threads (1 block/CU, LDS-capped -> VGPR
// budget 512/thread, zero spills). 16 waves = 2 rowg x 8 colg; wave = 64 rows
// x 32 cols, single col pass. h0/h1 in LDS (stride 264) for all 10 steps.
// bf16 MFMA 16x16x32, fp32 accum/elementwise.

#define HS 264   // LDS row stride in shorts (33 granules/row -> (row+q)%8 spread)

typedef __attribute__((ext_vector_type(8))) short short8;
typedef __attribute__((ext_vector_type(4))) float fvec4;

__device__ __forceinline__ float bf2f(unsigned short u) {
    union { unsigned int u; float f; } x; x.u = ((unsigned int)u) << 16; return x.f;
}
__device__ __forceinline__ unsigned short f2bf(float f) {
    union { float f; unsigned int u; } x; x.f = f;
    unsigned int r = x.u + 0x7fffu + ((x.u >> 16) & 1u);   // RNE
    return (unsigned short)(r >> 16);
}
__device__ __forceinline__ unsigned short f2bf_rn(float f) {  // round-half-up, 2 VALU
    union { float f; unsigned int u; } x; x.f = f;
    return (unsigned short)((x.u + 0x8000u) >> 16);
}
__device__ __forceinline__ float sigm(float x)   { return __builtin_amdgcn_rcpf(1.f + __expf(-x)); }
__device__ __forceinline__ float tanh_f(float x) { return 2.f * __builtin_amdgcn_rcpf(1.f + __expf(-2.f * x)) - 1.f; }

__device__ __forceinline__ short8 ld8(const unsigned short* p) {
    return *reinterpret_cast<const short8*>(p);
}
__device__ __forceinline__ fvec4 mfma16(short8 a, short8 b, fvec4 c) {
    return __builtin_amdgcn_mfma_f32_16x16x32_bf16(a, b, c, 0, 0, 0);
}

// ---------------- weight cast fp32 -> bf16 ----------------
// ws short layout: W1[262144] W2[65536] Winit[131072] Wih0[6144]
//                  Whh0[196608] Wih1[196608] Whh1[196608] Wa[2048]
__global__ __launch_bounds__(256) void k_prep(
    const float* __restrict__ W1, const float* __restrict__ W2,
    const float* __restrict__ Winit, const float* __restrict__ Wih0,
    const float* __restrict__ Whh0, const float* __restrict__ Wih1,
    const float* __restrict__ Whh1, const float* __restrict__ Wa,
    unsigned short* __restrict__ wb)
{
    int i = blockIdx.x * 256 + threadIdx.x;
    if (i >= 1056768) return;
    float v;
    if      (i <  262144) v = W1[i];
    else if (i <  327680) v = W2[i - 262144];
    else if (i <  458752) v = Winit[i - 327680];
    else if (i <  464896) v = Wih0[i - 458752];
    else if (i <  661504) v = Whh0[i - 464896];
    else if (i <  858112) v = Wih1[i - 661504];
    else if (i < 1054720) v = Whh1[i - 858112];
    else                  v = Wa[i - 1054720];
    wb[i] = f2bf(v);
}

// ---------------- encoder: fc1 -> LN -> ReLU -> fc2 -> ReLU -> init -----------
// block = 64 rows, 8 waves. Unchanged structure; fc1 input cvt uses cheap
// round-half-up (2 VALU/value instead of 4).
__global__ __launch_bounds__(512, 2) void k_encode(
    const float* __restrict__ ini, const float* __restrict__ fin,
    const unsigned short* __restrict__ W1b, const float* __restrict__ b1,
    const float* __restrict__ lng, const float* __restrict__ lnb,
    const unsigned short* __restrict__ W2b, const float* __restrict__ b2,
    const unsigned short* __restrict__ Winitb, const float* __restrict__ binit,
    unsigned short* __restrict__ h0g, unsigned short* __restrict__ h1g)
{
    __shared__ unsigned short hb[64 * HS];
    __shared__ float ps[64][8][2];
    __shared__ float st[64][2];
    const int tid = threadIdx.x, lane = tid & 63, w = tid >> 6;
    const int l15 = lane & 15, q = lane >> 4;
    const int rows0 = blockIdx.x * 64;
    const int c0 = w * 32;
    const fvec4 fz = {0.f, 0.f, 0.f, 0.f};

    fvec4 acc[4][2];
#pragma unroll
    for (int rt = 0; rt < 4; ++rt) { acc[rt][0] = fz; acc[rt][1] = fz; }
    for (int kc = 0; kc < 32; ++kc) {
        const int k0 = kc * 32 + q * 8;
        short8 a8[4];
#pragma unroll
        for (int rt = 0; rt < 4; ++rt) {
            const int grow = rows0 + rt * 16 + l15;
            const float* src = (k0 < 512) ? (ini + grow * 512 + k0)
                                          : (fin + grow * 512 + (k0 - 512));
            fvec4 v0 = *reinterpret_cast<const fvec4*>(src);
            fvec4 v1 = *reinterpret_cast<const fvec4*>(src + 4);
            short8 t;
            t[0]=(short)f2bf_rn(v0[0]); t[1]=(short)f2bf_rn(v0[1]); t[2]=(short)f2bf_rn(v0[2]); t[3]=(short)f2bf_rn(v0[3]);
            t[4]=(short)f2bf_rn(v1[0]); t[5]=(short)f2bf_rn(v1[1]); t[6]=(short)f2bf_rn(v1[2]); t[7]=(short)f2bf_rn(v1[3]);
            a8[rt] = t;
        }
#pragma unroll
        for (int ct = 0; ct < 2; ++ct) {
            short8 b8 = ld8(W1b + (c0 + ct * 16 + l15) * 1024 + k0);
#pragma unroll
            for (int rt = 0; rt < 4; ++rt) acc[rt][ct] = mfma16(a8[rt], b8, acc[rt][ct]);
        }
    }
    float bv[2] = { b1[c0 + l15], b1[c0 + 16 + l15] };
#pragma unroll
    for (int rt = 0; rt < 4; ++rt)
#pragma unroll
        for (int r = 0; r < 4; ++r) {
            float s = 0.f, s2 = 0.f;
#pragma unroll
            for (int ct = 0; ct < 2; ++ct) {
                float v = acc[rt][ct][r] + bv[ct];
                acc[rt][ct][r] = v;
                s += v; s2 += v * v;
            }
#pragma unroll
            for (int off = 1; off < 16; off <<= 1) {
                s  += __shfl_xor(s,  off, 64);
                s2 += __shfl_xor(s2, off, 64);
            }
            if (l15 == 0) {
                int row = rt * 16 + q * 4 + r;
                ps[row][w][0] = s; ps[row][w][1] = s2;
            }
        }
    __syncthreads();
    if (tid < 64) {
        float s = 0.f, s2 = 0.f;
#pragma unroll
        for (int j = 0; j < 8; ++j) { s += ps[tid][j][0]; s2 += ps[tid][j][1]; }
        float mu = s * (1.f / 256.f);
        float var = s2 * (1.f / 256.f) - mu * mu;
        st[tid][0] = mu; st[tid][1] = rsqrtf(var + 1e-5f);
    }
    __syncthreads();
    {
        float gv[2]  = { lng[c0 + l15], lng[c0 + 16 + l15] };
        float bbv[2] = { lnb[c0 + l15], lnb[c0 + 16 + l15] };
#pragma unroll
        for (int rt = 0; rt < 4; ++rt)
#pragma unroll
            for (int ct = 0; ct < 2; ++ct)
#pragma unroll
                for (int r = 0; r < 4; ++r) {
                    int row = rt * 16 + q * 4 + r;
                    float v = (acc[rt][ct][r] - st[row][0]) * st[row][1] * gv[ct] + bbv[ct];
                    v = fmaxf(v, 0.f);
                    hb[row * HS + c0 + ct * 16 + l15] = f2bf(v);
                }
    }
    __syncthreads();
    fvec4 acc2[4][2];
#pragma unroll
    for (int rt = 0; rt < 4; ++rt) { acc2[rt][0] = fz; acc2[rt][1] = fz; }
    for (int kc = 0; kc < 8; ++kc) {
        const int k0 = kc * 32 + q * 8;
        short8 a8[4];
#pragma unroll
        for (int rt = 0; rt < 4; ++rt) a8[rt] = ld8(hb + (rt * 16 + l15) * HS + k0);
#pragma unroll
        for (int ct = 0; ct < 2; ++ct) {
            short8 b8 = ld8(W2b + (c0 + ct * 16 + l15) * 256 + k0);
#pragma unroll
            for (int rt = 0; rt < 4; ++rt) acc2[rt][ct] = mfma16(a8[rt], b8, acc2[rt][ct]);
        }
    }
    {
        float b2v[2] = { b2[c0 + l15], b2[c0 + 16 + l15] };
        unsigned short stg[4][2][4];
#pragma unroll
        for (int rt = 0; rt < 4; ++rt)
#pragma unroll
            for (int ct = 0; ct < 2; ++ct)
#pragma unroll
                for (int r = 0; r < 4; ++r)
                    stg[rt][ct][r] = f2bf(fmaxf(acc2[rt][ct][r] + b2v[ct], 0.f));
        __syncthreads();
#pragma unroll
        for (int rt = 0; rt < 4; ++rt)
#pragma unroll
            for (int ct = 0; ct < 2; ++ct)
#pragma unroll
                for (int r = 0; r < 4; ++r)
                    hb[(rt * 16 + q * 4 + r) * HS + c0 + ct * 16 + l15] = stg[rt][ct][r];
    }
    __syncthreads();
    const int c0i = w * 64;
    fvec4 a3[4][4];
#pragma unroll
    for (int rt = 0; rt < 4; ++rt)
#pragma unroll
        for (int ct = 0; ct < 4; ++ct) a3[rt][ct] = fz;
    for (int kc = 0; kc < 8; ++kc) {
        const int k0 = kc * 32 + q * 8;
        short8 a8[4];
#pragma unroll
        for (int rt = 0; rt < 4; ++rt) a8[rt] = ld8(hb + (rt * 16 + l15) * HS + k0);
#pragma unroll
        for (int ct = 0; ct < 4; ++ct) {
            short8 b8 = ld8(Winitb + (c0i + ct * 16 + l15) * 256 + k0);
#pragma unroll
            for (int rt = 0; rt < 4; ++rt) a3[rt][ct] = mfma16(a8[rt], b8, a3[rt][ct]);
        }
    }
#pragma unroll
    for (int ct = 0; ct < 4; ++ct) {
        const int j = c0i + ct * 16 + l15;
        const float bz = binit[j];
        const int half = j >> 8, cc = j & 255;
#pragma unroll
        for (int rt = 0; rt < 4; ++rt)
#pragma unroll
            for (int r = 0; r < 4; ++r) {
                const int i = rows0 + rt * 16 + q * 4 + r;
                const unsigned short v = f2bf(a3[rt][ct][r] + bz);
                if (i < 16384) h0g[(2 * i + half) * 256 + cc] = v;
                else           h1g[(2 * (i - 16384) + half) * 256 + cc] = v;
            }
    }
}

// ---------------- fused 10-step rollout (v4) -------------------------------
// 256 blocks x 1024 threads; 16 waves = 2 rowg x 8 colg.
// wave = 64 rows (rt=4) x 32 cols (ct=2), single pass over its cols.
__global__ __launch_bounds__(1024, 4) void k_roll(
    const unsigned short* __restrict__ h0g, const unsigned short* __restrict__ h1g,
    const unsigned short* __restrict__ Wih0b, const unsigned short* __restrict__ Whh0b,
    const unsigned short* __restrict__ Wih1b, const unsigned short* __restrict__ Whh1b,
    const unsigned short* __restrict__ Wab,
    const float* __restrict__ bih0, const float* __restrict__ bhh0,
    const float* __restrict__ bih1, const float* __restrict__ bhh1,
    const float* __restrict__ ba, float* __restrict__ out)
{
    __shared__ unsigned short h0s[128 * HS];
    __shared__ unsigned short h1s[128 * HS];
    __shared__ unsigned short avs[128 * 8];
    const int tid = threadIdx.x, lane = tid & 63, w = tid >> 6;
    const int l15 = lane & 15, q = lane >> 4;
    const int rowg = w >> 3, row0 = rowg * 64;
    const int cb = (w & 7) * 32;
    const int rows0 = blockIdx.x * 128;
    const fvec4 fz = {0.f, 0.f, 0.f, 0.f};
    const short8 z8 = {0,0,0,0,0,0,0,0};

    // ---- load h state global -> LDS ----
    for (int it = tid; it < 128 * 32; it += 1024) {
        const int row = it >> 5, g = (it & 31) * 8;
        *reinterpret_cast<short8*>(h0s + row * HS + g) = ld8(h0g + (rows0 + row) * 256 + g);
        *reinterpret_cast<short8*>(h1s + row * HS + g) = ld8(h1g + (rows0 + row) * 256 + g);
    }
    // ---- per-lane bias constants ----
    float br0[2], bz0[2], bi0[2], bh0[2], br1[2], bz1[2], bi1[2], bh1[2];
#pragma unroll
    for (int ct = 0; ct < 2; ++ct) {
        const int c = cb + ct * 16 + l15;
        br0[ct] = bih0[c] + bhh0[c];
        bz0[ct] = bih0[256 + c] + bhh0[256 + c];
        bi0[ct] = bih0[512 + c];
        bh0[ct] = bhh0[512 + c];
        br1[ct] = bih1[c] + bhh1[c];
        bz1[ct] = bih1[256 + c] + bhh1[256 + c];
        bi1[ct] = bih1[512 + c];
        bh1[ct] = bhh1[512 + c];
    }
    const float bav = ba[l15 & 7];
    __syncthreads();

    for (int t = 0; t < 10; ++t) {
        unsigned int stg[4][2][2];
        // ================= GRU cell 0 =================
        {
            fvec4 aR[4][2], aZ[4][2], aNi[4][2], aNh[4][2];
#pragma unroll
            for (int rt = 0; rt < 4; ++rt)
#pragma unroll
                for (int ct = 0; ct < 2; ++ct) { aR[rt][ct]=fz; aZ[rt][ct]=fz; aNi[rt][ct]=fz; aNh[rt][ct]=fz; }
            for (int kc = 0; kc < 8; ++kc) {
                const int k0 = kc * 32 + q * 8;
                short8 ah[4];
#pragma unroll
                for (int rt = 0; rt < 4; ++rt)
                    ah[rt] = ld8(h0s + (row0 + rt * 16 + l15) * HS + k0);
#pragma unroll
                for (int ct = 0; ct < 2; ++ct) {
                    const unsigned short* wp = Whh0b + (cb + ct * 16 + l15) * 256 + k0;
                    short8 wr = ld8(wp);
                    short8 wz = ld8(wp + 65536);
                    short8 wn = ld8(wp + 131072);
#pragma unroll
                    for (int rt = 0; rt < 4; ++rt) {
                        aR[rt][ct]  = mfma16(ah[rt], wr, aR[rt][ct]);
                        aZ[rt][ct]  = mfma16(ah[rt], wz, aZ[rt][ct]);
                        aNh[rt][ct] = mfma16(ah[rt], wn, aNh[rt][ct]);
                    }
                }
            }
            if (t > 0) {       // action GEMM K=8 in one K=32 chunk (quads 1-3 -> 0)
                short8 av[4];
#pragma unroll
                for (int rt = 0; rt < 4; ++rt) {
                    short8 v = ld8(avs + (row0 + rt * 16 + l15) * 8);
                    av[rt] = (q == 0) ? v : z8;
                }
#pragma unroll
                for (int ct = 0; ct < 2; ++ct) {
                    const unsigned short* wp = Wih0b + (cb + ct * 16 + l15) * 8;
                    short8 wr = ld8(wp);
                    short8 wz = ld8(wp + 2048);
                    short8 wn = ld8(wp + 4096);
#pragma unroll
                    for (int rt = 0; rt < 4; ++rt) {
                        aR[rt][ct]  = mfma16(av[rt], wr, aR[rt][ct]);
                        aZ[rt][ct]  = mfma16(av[rt], wz, aZ[rt][ct]);
                        aNi[rt][ct] = mfma16(av[rt], wn, aNi[rt][ct]);
                    }
                }
            }
#pragma unroll
            for (int rt = 0; rt < 4; ++rt)
#pragma unroll
                for (int ct = 0; ct < 2; ++ct) {
                    const int c = cb + ct * 16 + l15;
                    unsigned int p0 = 0, p1 = 0;
#pragma unroll
                    for (int r = 0; r < 4; ++r) {
                        const int row = row0 + rt * 16 + q * 4 + r;
                        const float hold = bf2f(h0s[row * HS + c]);
                        const float rr = sigm(aR[rt][ct][r] + br0[ct]);
                        const float zz = sigm(aZ[rt][ct][r] + bz0[ct]);
                        const float nn = tanh_f(aNi[rt][ct][r] + bi0[ct] + rr * (aNh[rt][ct][r] + bh0[ct]));
                        const unsigned int v = f2bf((1.f - zz) * nn + zz * hold);
                        if (r < 2) p0 |= v << (16 * r); else p1 |= v << (16 * (r - 2));
                    }
                    stg[rt][ct][0] = p0; stg[rt][ct][1] = p1;
                }
        }
        __syncthreads();   // all reads of h0s done
#pragma unroll
        for (int rt = 0; rt < 4; ++rt)
#pragma unroll
            for (int ct = 0; ct < 2; ++ct) {
                const int c = cb + ct * 16 + l15;
#pragma unroll
                for (int r = 0; r < 4; ++r)
                    h0s[(row0 + rt * 16 + q * 4 + r) * HS + c] =
                        (unsigned short)(stg[rt][ct][r >> 1] >> (16 * (r & 1)));
            }
        __syncthreads();   // h0s = h0n
        // ================= GRU cell 1 =================
        {
            fvec4 aR[4][2], aZ[4][2], aNi[4][2], aNh[4][2];
#pragma unroll
            for (int rt = 0; rt < 4; ++rt)
#pragma unroll
                for (int ct = 0; ct < 2; ++ct) { aR[rt][ct]=fz; aZ[rt][ct]=fz; aNi[rt][ct]=fz; aNh[rt][ct]=fz; }
            for (int kc = 0; kc < 8; ++kc) {
                const int k0 = kc * 32 + q * 8;
                short8 ai[4], ah[4];
#pragma unroll
                for (int rt = 0; rt < 4; ++rt) {
                    const int rr = (row0 + rt * 16 + l15) * HS + k0;
                    ai[rt] = ld8(h0s + rr);
                    ah[rt] = ld8(h1s + rr);
                }
#pragma unroll
                for (int ct = 0; ct < 2; ++ct) {
                    const unsigned short* wi = Wih1b + (cb + ct * 16 + l15) * 256 + k0;
                    const unsigned short* wh = Whh1b + (cb + ct * 16 + l15) * 256 + k0;
                    short8 wir = ld8(wi);
                    short8 whr = ld8(wh);
                    short8 wiz = ld8(wi + 65536);
                    short8 whz = ld8(wh + 65536);
                    short8 win = ld8(wi + 131072);
                    short8 whn = ld8(wh + 131072);
#pragma unroll
                    for (int rt = 0; rt < 4; ++rt) {
                        aR[rt][ct]  = mfma16(ai[rt], wir, aR[rt][ct]);
                        aR[rt][ct]  = mfma16(ah[rt], whr, aR[rt][ct]);
                        aZ[rt][ct]  = mfma16(ai[rt], wiz, aZ[rt][ct]);
                        aZ[rt][ct]  = mfma16(ah[rt], whz, aZ[rt][ct]);
                        aNi[rt][ct] = mfma16(ai[rt], win, aNi[rt][ct]);
                        aNh[rt][ct] = mfma16(ah[rt], whn, aNh[rt][ct]);
                    }
                }
            }
#pragma unroll
            for (int rt = 0; rt < 4; ++rt)
#pragma unroll
                for (int ct = 0; ct < 2; ++ct) {
                    const int c = cb + ct * 16 + l15;
                    unsigned int p0 = 0, p1 = 0;
#pragma unroll
                    for (int r = 0; r < 4; ++r) {
                        const int row = row0 + rt * 16 + q * 4 + r;
                        const float hold = bf2f(h1s[row * HS + c]);
                        const float rr = sigm(aR[rt][ct][r] + br1[ct]);
                        const float zz = sigm(aZ[rt][ct][r] + bz1[ct]);
                        const float nn = tanh_f(aNi[rt][ct][r] + bi1[ct] + rr * (aNh[rt][ct][r] + bh1[ct]));
                        const unsigned int v = f2bf((1.f - zz) * nn + zz * hold);
                        if (r < 2) p0 |= v << (16 * r); else p1 |= v << (16 * (r - 2));
                    }
                    stg[rt][ct][0] = p0; stg[rt][ct][1] = p1;
                }
        }
        __syncthreads();   // all reads of h1s done
#pragma unroll
        for (int rt = 0; rt < 4; ++rt)
#pragma unroll
            for (int ct = 0; ct < 2; ++ct) {
                const int c = cb + ct * 16 + l15;
#pragma unroll
                for (int r = 0; r < 4; ++r)
                    h1s[(row0 + rt * 16 + q * 4 + r) * HS + c] =
                        (unsigned short)(stg[rt][ct][r >> 1] >> (16 * (r & 1)));
            }
        __syncthreads();   // h1s = h1n
        // ================= logits + softmax -> a (waves 0-7, 16 rows each) ====
        if (w < 8) {
            fvec4 f = fz;
            for (int kc = 0; kc < 8; ++kc) {
                const int k0 = kc * 32 + q * 8;
                short8 a8 = ld8(h1s + (w * 16 + l15) * HS + k0);
                short8 b8 = ld8(Wab + (l15 & 7) * 256 + k0);   // cols 8-15 dup, ignored
                f = mfma16(a8, b8, f);
            }
#pragma unroll
            for (int r = 0; r < 4; ++r) {
                float s = f[r] + bav;
                float m = s;
                m = fmaxf(m, __shfl_xor(m, 1, 64));
                m = fmaxf(m, __shfl_xor(m, 2, 64));
                m = fmaxf(m, __shfl_xor(m, 4, 64));
                float e = __expf(s - m);
                float se = e;
                se += __shfl_xor(se, 1, 64);
                se += __shfl_xor(se, 2, 64);
                se += __shfl_xor(se, 4, 64);
                if (l15 < 8) {
                    const int lrow = w * 16 + q * 4 + r;
                    out[(rows0 + lrow) * 80 + t * 8 + l15] = s;
                    avs[lrow * 8 + l15] = f2bf(e * __builtin_amdgcn_rcpf(se));
                }
            }
        }
        __syncthreads();   // avs ready for next step
    }
}

// ---------------- host side -----------------------------------------------
extern "C" void kernel_launch(void* const* d_in, const int* in_sizes, int n_in,
                              void* d_out, int out_size, void* d_ws, size_t ws_size,
                              hipStream_t stream)
{
    const float* ini   = (const float*)d_in[0];
    const float* fin   = (const float*)d_in[1];
    /* d_in[2] = horizon (always 10) */
    const float* W1    = (const float*)d_in[3];
    const float* b1    = (const float*)d_in[4];
    const float* lng   = (const float*)d_in[5];
    const float* lnb   = (const float*)d_in[6];
    const float* W2    = (const float*)d_in[7];
    const float* b2    = (const float*)d_in[8];
    const float* Wih0  = (const float*)d_in[9];
    const float* Whh0  = (const float*)d_in[10];
    const float* bih0  = (const float*)d_in[11];
    const float* bhh0  = (const float*)d_in[12];
    const float* Wih1  = (const float*)d_in[13];
    const float* Whh1  = (const float*)d_in[14];
    const float* bih1  = (const float*)d_in[15];
    const float* bhh1  = (const float*)d_in[16];
    const float* Wa    = (const float*)d_in[17];
    const float* ba    = (const float*)d_in[18];
    const float* Winit = (const float*)d_in[19];
    const float* binit = (const float*)d_in[20];
    float* out = (float*)d_out;

    char* ws = (char*)d_ws;
    unsigned short* wb     = (unsigned short*)ws;
    unsigned short* W1b    = wb;
    unsigned short* W2b    = wb + 262144;
    unsigned short* Winitb = wb + 327680;
    unsigned short* Wih0b  = wb + 458752;
    unsigned short* Whh0b  = wb + 464896;
    unsigned short* Wih1b  = wb + 661504;
    unsigned short* Whh1b  = wb + 858112;
    unsigned short* Wab    = wb + 1054720;
    unsigned short* h0g = (unsigned short*)(ws + 2113536);
    unsigned short* h1g = (unsigned short*)(ws + 18890752);

    k_prep<<<dim3(4128), dim3(256), 0, stream>>>(W1, W2, Winit, Wih0, Whh0, Wih1, Whh1, Wa, wb);
    k_encode<<<dim3(512), dim3(512), 0, stream>>>(ini, fin, W1b, b1, lng, lnb, W2b, b2,
                                                  Winitb, binit, h0g, h1g);
    k_roll<<<dim3(256), dim3(1024), 0, stream>>>(h0g, h1g, Wih0b, Whh0b, Wih1b, Whh1b, Wab,
                                                 bih0, bhh0, bih1, bhh1, ba, out);
}

// Round 5
// 1246.783 us; speedup vs baseline: 3.7949x; 3.7949x over previous
//
#include <hip/hip_runtime.h>

// InverseTransitionModel, B=32768, H=256, 10 GRU steps.
// v5: register-BUDGETED fused rollout. Pool = 512 VGPR/SIMD; at
// __launch_bounds__(512,2) each wave gets 256 (VGPR+AGPR). Wave = 64 rows x
// 32 cols: 128 AGPR accums + 32 A-frag + 48 weight + ~30 addr = ~240. kc
// loops pinned #pragma unroll 1 (no cross-iter hoisting), biases in LDS,
// new-h stashed in dead accumulator regs across barriers. Zero spills.

#define HS 264   // LDS row stride in shorts (16B-aligned rows; A-frag b128 conflict-free)

typedef __attribute__((ext_vector_type(8))) short short8;
typedef __attribute__((ext_vector_type(4))) float fvec4;

__device__ __forceinline__ float bf2f(unsigned short u) {
    union { unsigned int u; float f; } x; x.u = ((unsigned int)u) << 16; return x.f;
}
__device__ __forceinline__ unsigned short f2bf(float f) {
    union { float f; unsigned int u; } x; x.f = f;
    unsigned int r = x.u + 0x7fffu + ((x.u >> 16) & 1u);   // RNE
    return (unsigned short)(r >> 16);
}
__device__ __forceinline__ float sigm(float x)   { return __builtin_amdgcn_rcpf(1.f + __expf(-x)); }
__device__ __forceinline__ float tanh_f(float x) { return 2.f * __builtin_amdgcn_rcpf(1.f + __expf(-2.f * x)) - 1.f; }

__device__ __forceinline__ short8 ld8(const unsigned short* p) {
    return *reinterpret_cast<const short8*>(p);
}
__device__ __forceinline__ fvec4 mfma16(short8 a, short8 b, fvec4 c) {
    return __builtin_amdgcn_mfma_f32_16x16x32_bf16(a, b, c, 0, 0, 0);
}

// ---------------- weight cast fp32 -> bf16 ----------------
// ws short layout: W1[262144] W2[65536] Winit[131072] Wih0[6144]
//                  Whh0[196608] Wih1[196608] Whh1[196608] Wa[2048]
__global__ __launch_bounds__(256) void k_prep(
    const float* __restrict__ W1, const float* __restrict__ W2,
    const float* __restrict__ Winit, const float* __restrict__ Wih0,
    const float* __restrict__ Whh0, const float* __restrict__ Wih1,
    const float* __restrict__ Whh1, const float* __restrict__ Wa,
    unsigned short* __restrict__ wb)
{
    int i = blockIdx.x * 256 + threadIdx.x;
    if (i >= 1056768) return;
    float v;
    if      (i <  262144) v = W1[i];
    else if (i <  327680) v = W2[i - 262144];
    else if (i <  458752) v = Winit[i - 327680];
    else if (i <  464896) v = Wih0[i - 458752];
    else if (i <  661504) v = Whh0[i - 464896];
    else if (i <  858112) v = Wih1[i - 661504];
    else if (i < 1054720) v = Whh1[i - 858112];
    else                  v = Wa[i - 1054720];
    wb[i] = f2bf(v);
}

// ---------------- encoder: fc1 -> LN -> ReLU -> fc2 -> ReLU -> init -----------
// block = 64 rows, 8 waves. fc1 global loads batched ahead of cvt+MFMA.
__global__ __launch_bounds__(512, 2) void k_encode(
    const float* __restrict__ ini, const float* __restrict__ fin,
    const unsigned short* __restrict__ W1b, const float* __restrict__ b1,
    const float* __restrict__ lng, const float* __restrict__ lnb,
    const unsigned short* __restrict__ W2b, const float* __restrict__ b2,
    const unsigned short* __restrict__ Winitb, const float* __restrict__ binit,
    unsigned short* __restrict__ h0g, unsigned short* __restrict__ h1g)
{
    __shared__ unsigned short hb[64 * HS];
    __shared__ float ps[64][8][2];
    __shared__ float st[64][2];
    const int tid = threadIdx.x, lane = tid & 63, w = tid >> 6;
    const int l15 = lane & 15, q = lane >> 4;
    const int rows0 = blockIdx.x * 64;
    const int c0 = w * 32;
    const fvec4 fz = {0.f, 0.f, 0.f, 0.f};

    fvec4 acc[4][2];
#pragma unroll
    for (int rt = 0; rt < 4; ++rt) { acc[rt][0] = fz; acc[rt][1] = fz; }
#pragma unroll 2
    for (int kc = 0; kc < 32; ++kc) {
        const int k0 = kc * 32 + q * 8;
        fvec4 v[4][2];
#pragma unroll
        for (int rt = 0; rt < 4; ++rt) {   // 8 independent 16B loads, batched
            const int grow = rows0 + rt * 16 + l15;
            const float* src = (k0 < 512) ? (ini + grow * 512 + k0)
                                          : (fin + grow * 512 + (k0 - 512));
            v[rt][0] = *reinterpret_cast<const fvec4*>(src);
            v[rt][1] = *reinterpret_cast<const fvec4*>(src + 4);
        }
        short8 b8a = ld8(W1b + (c0 + l15) * 1024 + k0);
        short8 b8b = ld8(W1b + (c0 + 16 + l15) * 1024 + k0);
        short8 a8[4];
#pragma unroll
        for (int rt = 0; rt < 4; ++rt) {
            short8 t;
            t[0]=(short)f2bf(v[rt][0][0]); t[1]=(short)f2bf(v[rt][0][1]);
            t[2]=(short)f2bf(v[rt][0][2]); t[3]=(short)f2bf(v[rt][0][3]);
            t[4]=(short)f2bf(v[rt][1][0]); t[5]=(short)f2bf(v[rt][1][1]);
            t[6]=(short)f2bf(v[rt][1][2]); t[7]=(short)f2bf(v[rt][1][3]);
            a8[rt] = t;
        }
#pragma unroll
        for (int rt = 0; rt < 4; ++rt) {
            acc[rt][0] = mfma16(a8[rt], b8a, acc[rt][0]);
            acc[rt][1] = mfma16(a8[rt], b8b, acc[rt][1]);
        }
    }
    float bv[2] = { b1[c0 + l15], b1[c0 + 16 + l15] };
#pragma unroll
    for (int rt = 0; rt < 4; ++rt)
#pragma unroll
        for (int r = 0; r < 4; ++r) {
            float s = 0.f, s2 = 0.f;
#pragma unroll
            for (int ct = 0; ct < 2; ++ct) {
                float v = acc[rt][ct][r] + bv[ct];
                acc[rt][ct][r] = v;
                s += v; s2 += v * v;
            }
#pragma unroll
            for (int off = 1; off < 16; off <<= 1) {
                s  += __shfl_xor(s,  off, 64);
                s2 += __shfl_xor(s2, off, 64);
            }
            if (l15 == 0) {
                int row = rt * 16 + q * 4 + r;
                ps[row][w][0] = s; ps[row][w][1] = s2;
            }
        }
    __syncthreads();
    if (tid < 64) {
        float s = 0.f, s2 = 0.f;
#pragma unroll
        for (int j = 0; j < 8; ++j) { s += ps[tid][j][0]; s2 += ps[tid][j][1]; }
        float mu = s * (1.f / 256.f);
        float var = s2 * (1.f / 256.f) - mu * mu;
        st[tid][0] = mu; st[tid][1] = rsqrtf(var + 1e-5f);
    }
    __syncthreads();
    {
        float gv[2]  = { lng[c0 + l15], lng[c0 + 16 + l15] };
        float bbv[2] = { lnb[c0 + l15], lnb[c0 + 16 + l15] };
#pragma unroll
        for (int rt = 0; rt < 4; ++rt)
#pragma unroll
            for (int ct = 0; ct < 2; ++ct)
#pragma unroll
                for (int r = 0; r < 4; ++r) {
                    int row = rt * 16 + q * 4 + r;
                    float v = (acc[rt][ct][r] - st[row][0]) * st[row][1] * gv[ct] + bbv[ct];
                    v = fmaxf(v, 0.f);
                    hb[row * HS + c0 + ct * 16 + l15] = f2bf(v);
                }
    }
    __syncthreads();
    fvec4 acc2[4][2];
#pragma unroll
    for (int rt = 0; rt < 4; ++rt) { acc2[rt][0] = fz; acc2[rt][1] = fz; }
#pragma unroll 2
    for (int kc = 0; kc < 8; ++kc) {
        const int k0 = kc * 32 + q * 8;
        short8 a8[4];
#pragma unroll
        for (int rt = 0; rt < 4; ++rt) a8[rt] = ld8(hb + (rt * 16 + l15) * HS + k0);
#pragma unroll
        for (int ct = 0; ct < 2; ++ct) {
            short8 b8 = ld8(W2b + (c0 + ct * 16 + l15) * 256 + k0);
#pragma unroll
            for (int rt = 0; rt < 4; ++rt) acc2[rt][ct] = mfma16(a8[rt], b8, acc2[rt][ct]);
        }
    }
    {
        float b2v[2] = { b2[c0 + l15], b2[c0 + 16 + l15] };
        unsigned short stg[4][2][4];
#pragma unroll
        for (int rt = 0; rt < 4; ++rt)
#pragma unroll
            for (int ct = 0; ct < 2; ++ct)
#pragma unroll
                for (int r = 0; r < 4; ++r)
                    stg[rt][ct][r] = f2bf(fmaxf(acc2[rt][ct][r] + b2v[ct], 0.f));
        __syncthreads();
#pragma unroll
        for (int rt = 0; rt < 4; ++rt)
#pragma unroll
            for (int ct = 0; ct < 2; ++ct)
#pragma unroll
                for (int r = 0; r < 4; ++r)
                    hb[(rt * 16 + q * 4 + r) * HS + c0 + ct * 16 + l15] = stg[rt][ct][r];
    }
    __syncthreads();
    const int c0i = w * 64;
    fvec4 a3[4][4];
#pragma unroll
    for (int rt = 0; rt < 4; ++rt)
#pragma unroll
        for (int ct = 0; ct < 4; ++ct) a3[rt][ct] = fz;
#pragma unroll 1
    for (int kc = 0; kc < 8; ++kc) {
        const int k0 = kc * 32 + q * 8;
        short8 a8[4];
#pragma unroll
        for (int rt = 0; rt < 4; ++rt) a8[rt] = ld8(hb + (rt * 16 + l15) * HS + k0);
#pragma unroll
        for (int ct = 0; ct < 4; ++ct) {
            short8 b8 = ld8(Winitb + (c0i + ct * 16 + l15) * 256 + k0);
#pragma unroll
            for (int rt = 0; rt < 4; ++rt) a3[rt][ct] = mfma16(a8[rt], b8, a3[rt][ct]);
        }
    }
#pragma unroll
    for (int ct = 0; ct < 4; ++ct) {
        const int j = c0i + ct * 16 + l15;
        const float bz = binit[j];
        const int half = j >> 8, cc = j & 255;
#pragma unroll
        for (int rt = 0; rt < 4; ++rt)
#pragma unroll
            for (int r = 0; r < 4; ++r) {
                const int i = rows0 + rt * 16 + q * 4 + r;
                const unsigned short v = f2bf(a3[rt][ct][r] + bz);
                if (i < 16384) h0g[(2 * i + half) * 256 + cc] = v;
                else           h1g[(2 * (i - 16384) + half) * 256 + cc] = v;
            }
    }
}

// ---------------- fused 10-step rollout (v5) -------------------------------
// 512 blocks x 512 threads (8 waves); wave = 64 rows (rt=4) x 32 cols (ct=2),
// cols = w*32. All state in LDS; biases in LDS; 5 barriers/step; no spills.
__global__ __launch_bounds__(512, 2) void k_roll(
    const unsigned short* __restrict__ h0g, const unsigned short* __restrict__ h1g,
    const unsigned short* __restrict__ Wih0b, const unsigned short* __restrict__ Whh0b,
    const unsigned short* __restrict__ Wih1b, const unsigned short* __restrict__ Whh1b,
    const unsigned short* __restrict__ Wab,
    const float* __restrict__ bih0, const float* __restrict__ bhh0,
    const float* __restrict__ bih1, const float* __restrict__ bhh1,
    const float* __restrict__ ba, float* __restrict__ out)
{
    __shared__ unsigned short h0s[64 * HS];
    __shared__ unsigned short h1s[64 * HS];
    __shared__ unsigned short avs[64 * 8];
    __shared__ float ldsb[2048];    // [cell0: br,bz,bi,bh][cell1: same] x 256
    const int tid = threadIdx.x, lane = tid & 63, w = tid >> 6;
    const int l15 = lane & 15, q = lane >> 4;
    const int rows0 = blockIdx.x * 64;
    const int cb = w * 32;
    const fvec4 fz = {0.f, 0.f, 0.f, 0.f};
    const short8 z8 = {0,0,0,0,0,0,0,0};

    // ---- h state global -> LDS; biases -> LDS ----
    for (int it = tid; it < 64 * 32; it += 512) {
        const int row = it >> 5, g = (it & 31) * 8;
        *reinterpret_cast<short8*>(h0s + row * HS + g) = ld8(h0g + (rows0 + row) * 256 + g);
        *reinterpret_cast<short8*>(h1s + row * HS + g) = ld8(h1g + (rows0 + row) * 256 + g);
    }
    if (tid < 256) {
        const int j = tid;
        ldsb[j]       = bih0[j] + bhh0[j];
        ldsb[256 + j] = bih0[256 + j] + bhh0[256 + j];
        ldsb[512 + j] = bih0[512 + j];
        ldsb[768 + j] = bhh0[512 + j];
    } else {
        const int j = tid - 256;
        ldsb[1024 + j] = bih1[j] + bhh1[j];
        ldsb[1280 + j] = bih1[256 + j] + bhh1[256 + j];
        ldsb[1536 + j] = bih1[512 + j];
        ldsb[1792 + j] = bhh1[512 + j];
    }
    const float bav = ba[l15 & 7];
    __syncthreads();

    for (int t = 0; t < 10; ++t) {
        // ================= GRU cell 0 =================
        {
            fvec4 aR[4][2], aZ[4][2], aNi[4][2], aNh[4][2];
#pragma unroll
            for (int rt = 0; rt < 4; ++rt)
#pragma unroll
                for (int ct = 0; ct < 2; ++ct) { aR[rt][ct]=fz; aZ[rt][ct]=fz; aNi[rt][ct]=fz; aNh[rt][ct]=fz; }
#pragma unroll 1
            for (int kc = 0; kc < 8; ++kc) {
                const int k0 = kc * 32 + q * 8;
                short8 wr[2], wz[2], wn[2];
#pragma unroll
                for (int ct = 0; ct < 2; ++ct) {
                    const unsigned short* wp = Whh0b + (cb + ct * 16 + l15) * 256 + k0;
                    wr[ct] = ld8(wp);
                    wz[ct] = ld8(wp + 65536);
                    wn[ct] = ld8(wp + 131072);
                }
                short8 ah[4];
#pragma unroll
                for (int rt = 0; rt < 4; ++rt)
                    ah[rt] = ld8(h0s + (rt * 16 + l15) * HS + k0);
#pragma unroll
                for (int ct = 0; ct < 2; ++ct)
#pragma unroll
                    for (int rt = 0; rt < 4; ++rt) {
                        aR[rt][ct]  = mfma16(ah[rt], wr[ct], aR[rt][ct]);
                        aZ[rt][ct]  = mfma16(ah[rt], wz[ct], aZ[rt][ct]);
                        aNh[rt][ct] = mfma16(ah[rt], wn[ct], aNh[rt][ct]);
                    }
            }
            if (t > 0) {       // action GEMM K=8 in one K=32 chunk (quads 1-3 -> 0)
                short8 av[4];
#pragma unroll
                for (int rt = 0; rt < 4; ++rt) {
                    short8 v = ld8(avs + (rt * 16 + l15) * 8);
                    av[rt] = (q == 0) ? v : z8;
                }
#pragma unroll
                for (int ct = 0; ct < 2; ++ct) {
                    const unsigned short* wp = Wih0b + (cb + ct * 16 + l15) * 8;
                    short8 wr = ld8(wp);
                    short8 wz = ld8(wp + 2048);
                    short8 wn = ld8(wp + 4096);
#pragma unroll
                    for (int rt = 0; rt < 4; ++rt) {
                        aR[rt][ct]  = mfma16(av[rt], wr, aR[rt][ct]);
                        aZ[rt][ct]  = mfma16(av[rt], wz, aZ[rt][ct]);
                        aNi[rt][ct] = mfma16(av[rt], wn, aNi[rt][ct]);
                    }
                }
            }
            // epilogue: hnew (fp32) stashed into dead aR regs
#pragma unroll
            for (int ct = 0; ct < 2; ++ct) {
                const int c = cb + ct * 16 + l15;
                const float br = ldsb[c], bz = ldsb[256 + c];
                const float bi = ldsb[512 + c], bh = ldsb[768 + c];
#pragma unroll
                for (int rt = 0; rt < 4; ++rt)
#pragma unroll
                    for (int r = 0; r < 4; ++r) {
                        const int row = rt * 16 + q * 4 + r;
                        const float hold = bf2f(h0s[row * HS + c]);
                        const float rr = sigm(aR[rt][ct][r] + br);
                        const float zz = sigm(aZ[rt][ct][r] + bz);
                        const float nn = tanh_f(aNi[rt][ct][r] + bi + rr * (aNh[rt][ct][r] + bh));
                        aR[rt][ct][r] = (1.f - zz) * nn + zz * hold;
                    }
            }
            __syncthreads();   // all reads of h0s done
#pragma unroll
            for (int ct = 0; ct < 2; ++ct) {
                const int c = cb + ct * 16 + l15;
#pragma unroll
                for (int rt = 0; rt < 4; ++rt)
#pragma unroll
                    for (int r = 0; r < 4; ++r)
                        h0s[(rt * 16 + q * 4 + r) * HS + c] = f2bf(aR[rt][ct][r]);
            }
        }
        __syncthreads();   // h0s = h0n
        // ================= GRU cell 1 =================
        {
            fvec4 aR[4][2], aZ[4][2], aNi[4][2], aNh[4][2];
#pragma unroll
            for (int rt = 0; rt < 4; ++rt)
#pragma unroll
                for (int ct = 0; ct < 2; ++ct) { aR[rt][ct]=fz; aZ[rt][ct]=fz; aNi[rt][ct]=fz; aNh[rt][ct]=fz; }
#pragma unroll 1
            for (int kc = 0; kc < 8; ++kc) {
                const int k0 = kc * 32 + q * 8;
                short8 wir[2], wiz[2], win[2], whr[2], whz[2], whn[2];
#pragma unroll
                for (int ct = 0; ct < 2; ++ct) {
                    const unsigned short* wi = Wih1b + (cb + ct * 16 + l15) * 256 + k0;
                    const unsigned short* wh = Whh1b + (cb + ct * 16 + l15) * 256 + k0;
                    wir[ct] = ld8(wi);
                    whr[ct] = ld8(wh);
                    wiz[ct] = ld8(wi + 65536);
                    whz[ct] = ld8(wh + 65536);
                    win[ct] = ld8(wi + 131072);
                    whn[ct] = ld8(wh + 131072);
                }
                short8 ai[4], ah[4];
#pragma unroll
                for (int rt = 0; rt < 4; ++rt) {
                    const int rr = (rt * 16 + l15) * HS + k0;
                    ai[rt] = ld8(h0s + rr);
                    ah[rt] = ld8(h1s + rr);
                }
#pragma unroll
                for (int ct = 0; ct < 2; ++ct)
#pragma unroll
                    for (int rt = 0; rt < 4; ++rt) {
                        aR[rt][ct]  = mfma16(ai[rt], wir[ct], aR[rt][ct]);
                        aR[rt][ct]  = mfma16(ah[rt], whr[ct], aR[rt][ct]);
                        aZ[rt][ct]  = mfma16(ai[rt], wiz[ct], aZ[rt][ct]);
                        aZ[rt][ct]  = mfma16(ah[rt], whz[ct], aZ[rt][ct]);
                        aNi[rt][ct] = mfma16(ai[rt], win[ct], aNi[rt][ct]);
                        aNh[rt][ct] = mfma16(ah[rt], whn[ct], aNh[rt][ct]);
                    }
            }
#pragma unroll
            for (int ct = 0; ct < 2; ++ct) {
                const int c = cb + ct * 16 + l15;
                const float br = ldsb[1024 + c], bz = ldsb[1280 + c];
                const float bi = ldsb[1536 + c], bh = ldsb[1792 + c];
#pragma unroll
                for (int rt = 0; rt < 4; ++rt)
#pragma unroll
                    for (int r = 0; r < 4; ++r) {
                        const int row = rt * 16 + q * 4 + r;
                        const float hold = bf2f(h1s[row * HS + c]);
                        const float rr = sigm(aR[rt][ct][r] + br);
                        const float zz = sigm(aZ[rt][ct][r] + bz);
                        const float nn = tanh_f(aNi[rt][ct][r] + bi + rr * (aNh[rt][ct][r] + bh));
                        aR[rt][ct][r] = (1.f - zz) * nn + zz * hold;
                    }
            }
            __syncthreads();   // all reads of h1s done
#pragma unroll
            for (int ct = 0; ct < 2; ++ct) {
                const int c = cb + ct * 16 + l15;
#pragma unroll
                for (int rt = 0; rt < 4; ++rt)
#pragma unroll
                    for (int r = 0; r < 4; ++r)
                        h1s[(rt * 16 + q * 4 + r) * HS + c] = f2bf(aR[rt][ct][r]);
            }
        }
        __syncthreads();   // h1s = h1n
        // ================= logits + softmax -> a (waves 0-3: 16 rows each) ====
        if (w < 4) {
            fvec4 f = fz;
#pragma unroll 1
            for (int kc = 0; kc < 8; ++kc) {
                const int k0 = kc * 32 + q * 8;
                short8 a8 = ld8(h1s + (w * 16 + l15) * HS + k0);
                short8 b8 = ld8(Wab + (l15 & 7) * 256 + k0);   // cols 8-15 dup, ignored
                f = mfma16(a8, b8, f);
            }
#pragma unroll
            for (int r = 0; r < 4; ++r) {
                float s = f[r] + bav;
                float m = s;
                m = fmaxf(m, __shfl_xor(m, 1, 64));
                m = fmaxf(m, __shfl_xor(m, 2, 64));
                m = fmaxf(m, __shfl_xor(m, 4, 64));
                float e = __expf(s - m);
                float se = e;
                se += __shfl_xor(se, 1, 64);
                se += __shfl_xor(se, 2, 64);
                se += __shfl_xor(se, 4, 64);
                if (l15 < 8) {
                    const int lrow = w * 16 + q * 4 + r;
                    out[(rows0 + lrow) * 80 + t * 8 + l15] = s;
                    avs[lrow * 8 + l15] = f2bf(e * __builtin_amdgcn_rcpf(se));
                }
            }
        }
        __syncthreads();   // avs ready for next step
    }
}

// ---------------- host side -----------------------------------------------
extern "C" void kernel_launch(void* const* d_in, const int* in_sizes, int n_in,
                              void* d_out, int out_size, void* d_ws, size_t ws_size,
                              hipStream_t stream)
{
    const float* ini   = (const float*)d_in[0];
    const float* fin   = (const float*)d_in[1];
    /* d_in[2] = horizon (always 10) */
    const float* W1    = (const float*)d_in[3];
    const float* b1    = (const float*)d_in[4];
    const float* lng   = (const float*)d_in[5];
    const float* lnb   = (const float*)d_in[6];
    const float* W2    = (const float*)d_in[7];
    const float* b2    = (const float*)d_in[8];
    const float* Wih0  = (const float*)d_in[9];
    const float* Whh0  = (const float*)d_in[10];
    const float* bih0  = (const float*)d_in[11];
    const float* bhh0  = (const float*)d_in[12];
    const float* Wih1  = (const float*)d_in[13];
    const float* Whh1  = (const float*)d_in[14];
    const float* bih1  = (const float*)d_in[15];
    const float* bhh1  = (const float*)d_in[16];
    const float* Wa    = (const float*)d_in[17];
    const float* ba    = (const float*)d_in[18];
    const float* Winit = (const float*)d_in[19];
    const float* binit = (const float*)d_in[20];
    float* out = (float*)d_out;

    char* ws = (char*)d_ws;
    unsigned short* wb     = (unsigned short*)ws;
    unsigned short* W1b    = wb;
    unsigned short* W2b    = wb + 262144;
    unsigned short* Winitb = wb + 327680;
    unsigned short* Wih0b  = wb + 458752;
    unsigned short* Whh0b  = wb + 464896;
    unsigned short* Wih1b  = wb + 661504;
    unsigned short* Whh1b  = wb + 858112;
    unsigned short* Wab    = wb + 1054720;
    unsigned short* h0g = (unsigned short*)(ws + 2113536);
    unsigned short* h1g = (unsigned short*)(ws + 18890752);

    k_prep<<<dim3(4128), dim3(256), 0, stream>>>(W1, W2, Winit, Wih0, Whh0, Wih1, Whh1, Wa, wb);
    k_encode<<<dim3(512), dim3(512), 0, stream>>>(ini, fin, W1b, b1, lng, lnb, W2b, b2,
                                                  Winitb, binit, h0g, h1g);
    k_roll<<<dim3(512), dim3(512), 0, stream>>>(h0g, h1g, Wih0b, Whh0b, Wih1b, Whh1b, Wab,
                                                bih0, bhh0, bih1, bhh1, ba, out);
}

// Round 6
// 881.511 us; speedup vs baseline: 5.3674x; 1.4144x over previous
//
#include <hip/hip_runtime.h>

// InverseTransitionModel, B=32768, H=256, 10 GRU steps.
// v6 = v5 (register-budgeted fused rollout, zero spills) + weights pre-packed
// in MFMA B-FRAGMENT ORDER: fragment for (16-col,32-K) tile = 64 lanes x 16B
// contiguous, so every weight load is a coalesced 1KB transaction (16 cache
// lines) instead of 64 scattered lines. Cell0 K-loop unroll 2 (fits budget).

#define HS 264   // LDS row stride in shorts (16B-aligned rows)

typedef __attribute__((ext_vector_type(8))) short short8;
typedef __attribute__((ext_vector_type(4))) float fvec4;

__device__ __forceinline__ float bf2f(unsigned short u) {
    union { unsigned int u; float f; } x; x.u = ((unsigned int)u) << 16; return x.f;
}
__device__ __forceinline__ unsigned short f2bf(float f) {
    union { float f; unsigned int u; } x; x.f = f;
    unsigned int r = x.u + 0x7fffu + ((x.u >> 16) & 1u);   // RNE
    return (unsigned short)(r >> 16);
}
__device__ __forceinline__ float sigm(float x)   { return __builtin_amdgcn_rcpf(1.f + __expf(-x)); }
__device__ __forceinline__ float tanh_f(float x) { return 2.f * __builtin_amdgcn_rcpf(1.f + __expf(-2.f * x)) - 1.f; }

__device__ __forceinline__ short8 ld8(const unsigned short* p) {
    return *reinterpret_cast<const short8*>(p);
}
__device__ __forceinline__ fvec4 mfma16(short8 a, short8 b, fvec4 c) {
    return __builtin_amdgcn_mfma_f32_16x16x32_bf16(a, b, c, 0, 0, 0);
}

// fragment-pack offset: element (n,k) of an NxK matrix -> packed index.
// tile (n>>4, k>>5) holds 512 elems, lane-major: lane = ((k>>3)&3)*16 + (n&15),
// j = k&7. Lane l's 8 elems are contiguous -> ld8 at base + lane*8 coalesces.
__device__ __forceinline__ int packoff(int e, int K) {
    const int n = e / K, k = e % K;   // K = 256 or 1024 -> shifts
    return (((n >> 4) * (K >> 5) + (k >> 5)) << 9)
         + (((((k >> 3) & 3) << 4) | (n & 15)) << 3) + (k & 7);
}

// ---------------- weight cast fp32 -> bf16 + fragment packing ----------------
// ws short layout (unchanged totals): W1[262144] W2[65536] Winit[131072]
//   Wih0[6144 plain] Whh0[196608] Wih1[196608] Whh1[196608] Wa[2048 plain]
__global__ __launch_bounds__(256) void k_prep(
    const float* __restrict__ W1, const float* __restrict__ W2,
    const float* __restrict__ Winit, const float* __restrict__ Wih0,
    const float* __restrict__ Whh0, const float* __restrict__ Wih1,
    const float* __restrict__ Whh1, const float* __restrict__ Wa,
    unsigned short* __restrict__ wb)
{
    int i = blockIdx.x * 256 + threadIdx.x;
    if (i >= 1056768) return;
    float v; int dst;
    if (i < 262144) {                       // W1: 256x1024, packed
        v = W1[i];                dst = packoff(i, 1024);
    } else if (i < 327680) {                // W2: 256x256, packed
        int e = i - 262144;  v = W2[e];    dst = 262144 + packoff(e, 256);
    } else if (i < 458752) {                // Winit: 512x256, packed
        int e = i - 327680;  v = Winit[e]; dst = 327680 + packoff(e, 256);
    } else if (i < 464896) {                // Wih0: 768x8, plain (already coalesced)
        v = Wih0[i - 458752];     dst = i;
    } else if (i < 661504) {                // Whh0: 768x256 (3 gates stacked), packed
        int e = i - 464896;  v = Whh0[e];  dst = 464896 + packoff(e, 256);
    } else if (i < 858112) {                // Wih1: 768x256, packed
        int e = i - 661504;  v = Wih1[e];  dst = 661504 + packoff(e, 256);
    } else if (i < 1054720) {               // Whh1: 768x256, packed
        int e = i - 858112;  v = Whh1[e];  dst = 858112 + packoff(e, 256);
    } else {                                // Wa: 8x256, plain
        v = Wa[i - 1054720];      dst = i;
    }
    wb[dst] = f2bf(v);
}

// ---------------- encoder: fc1 -> LN -> ReLU -> fc2 -> ReLU -> init -----------
// block = 64 rows, 8 waves; wave w -> cols [w*32, w*32+32). Packed-W loads.
__global__ __launch_bounds__(512, 2) void k_encode(
    const float* __restrict__ ini, const float* __restrict__ fin,
    const unsigned short* __restrict__ W1b, const float* __restrict__ b1,
    const float* __restrict__ lng, const float* __restrict__ lnb,
    const unsigned short* __restrict__ W2b, const float* __restrict__ b2,
    const unsigned short* __restrict__ Winitb, const float* __restrict__ binit,
    unsigned short* __restrict__ h0g, unsigned short* __restrict__ h1g)
{
    __shared__ unsigned short hb[64 * HS];
    __shared__ float ps[64][8][2];
    __shared__ float st[64][2];
    const int tid = threadIdx.x, lane = tid & 63, w = tid >> 6;
    const int l15 = lane & 15, q = lane >> 4;
    const int rows0 = blockIdx.x * 64;
    const int c0 = w * 32;
    const fvec4 fz = {0.f, 0.f, 0.f, 0.f};

    fvec4 acc[4][2];
#pragma unroll
    for (int rt = 0; rt < 4; ++rt) { acc[rt][0] = fz; acc[rt][1] = fz; }
#pragma unroll 2
    for (int kc = 0; kc < 32; ++kc) {
        const int k0 = kc * 32 + q * 8;
        fvec4 v[4][2];
#pragma unroll
        for (int rt = 0; rt < 4; ++rt) {   // 8 independent 16B loads, batched
            const int grow = rows0 + rt * 16 + l15;
            const float* src = (k0 < 512) ? (ini + grow * 512 + k0)
                                          : (fin + grow * 512 + (k0 - 512));
            v[rt][0] = *reinterpret_cast<const fvec4*>(src);
            v[rt][1] = *reinterpret_cast<const fvec4*>(src + 4);
        }
        short8 b8a = ld8(W1b + (((w * 2 + 0) * 32 + kc) * 64 + lane) * 8);
        short8 b8b = ld8(W1b + (((w * 2 + 1) * 32 + kc) * 64 + lane) * 8);
        short8 a8[4];
#pragma unroll
        for (int rt = 0; rt < 4; ++rt) {
            short8 t;
            t[0]=(short)f2bf(v[rt][0][0]); t[1]=(short)f2bf(v[rt][0][1]);
            t[2]=(short)f2bf(v[rt][0][2]); t[3]=(short)f2bf(v[rt][0][3]);
            t[4]=(short)f2bf(v[rt][1][0]); t[5]=(short)f2bf(v[rt][1][1]);
            t[6]=(short)f2bf(v[rt][1][2]); t[7]=(short)f2bf(v[rt][1][3]);
            a8[rt] = t;
        }
#pragma unroll
        for (int rt = 0; rt < 4; ++rt) {
            acc[rt][0] = mfma16(a8[rt], b8a, acc[rt][0]);
            acc[rt][1] = mfma16(a8[rt], b8b, acc[rt][1]);
        }
    }
    float bv[2] = { b1[c0 + l15], b1[c0 + 16 + l15] };
#pragma unroll
    for (int rt = 0; rt < 4; ++rt)
#pragma unroll
        for (int r = 0; r < 4; ++r) {
            float s = 0.f, s2 = 0.f;
#pragma unroll
            for (int ct = 0; ct < 2; ++ct) {
                float v = acc[rt][ct][r] + bv[ct];
                acc[rt][ct][r] = v;
                s += v; s2 += v * v;
            }
#pragma unroll
            for (int off = 1; off < 16; off <<= 1) {
                s  += __shfl_xor(s,  off, 64);
                s2 += __shfl_xor(s2, off, 64);
            }
            if (l15 == 0) {
                int row = rt * 16 + q * 4 + r;
                ps[row][w][0] = s; ps[row][w][1] = s2;
            }
        }
    __syncthreads();
    if (tid < 64) {
        float s = 0.f, s2 = 0.f;
#pragma unroll
        for (int j = 0; j < 8; ++j) { s += ps[tid][j][0]; s2 += ps[tid][j][1]; }
        float mu = s * (1.f / 256.f);
        float var = s2 * (1.f / 256.f) - mu * mu;
        st[tid][0] = mu; st[tid][1] = rsqrtf(var + 1e-5f);
    }
    __syncthreads();
    {
        float gv[2]  = { lng[c0 + l15], lng[c0 + 16 + l15] };
        float bbv[2] = { lnb[c0 + l15], lnb[c0 + 16 + l15] };
#pragma unroll
        for (int rt = 0; rt < 4; ++rt)
#pragma unroll
            for (int ct = 0; ct < 2; ++ct)
#pragma unroll
                for (int r = 0; r < 4; ++r) {
                    int row = rt * 16 + q * 4 + r;
                    float v = (acc[rt][ct][r] - st[row][0]) * st[row][1] * gv[ct] + bbv[ct];
                    v = fmaxf(v, 0.f);
                    hb[row * HS + c0 + ct * 16 + l15] = f2bf(v);
                }
    }
    __syncthreads();
    fvec4 acc2[4][2];
#pragma unroll
    for (int rt = 0; rt < 4; ++rt) { acc2[rt][0] = fz; acc2[rt][1] = fz; }
#pragma unroll 2
    for (int kc = 0; kc < 8; ++kc) {
        const int k0 = kc * 32 + q * 8;
        short8 a8[4];
#pragma unroll
        for (int rt = 0; rt < 4; ++rt) a8[rt] = ld8(hb + (rt * 16 + l15) * HS + k0);
#pragma unroll
        for (int ct = 0; ct < 2; ++ct) {
            short8 b8 = ld8(W2b + (((w * 2 + ct) * 8 + kc) * 64 + lane) * 8);
#pragma unroll
            for (int rt = 0; rt < 4; ++rt) acc2[rt][ct] = mfma16(a8[rt], b8, acc2[rt][ct]);
        }
    }
    {
        float b2v[2] = { b2[c0 + l15], b2[c0 + 16 + l15] };
        unsigned short stg[4][2][4];
#pragma unroll
        for (int rt = 0; rt < 4; ++rt)
#pragma unroll
            for (int ct = 0; ct < 2; ++ct)
#pragma unroll
                for (int r = 0; r < 4; ++r)
                    stg[rt][ct][r] = f2bf(fmaxf(acc2[rt][ct][r] + b2v[ct], 0.f));
        __syncthreads();
#pragma unroll
        for (int rt = 0; rt < 4; ++rt)
#pragma unroll
            for (int ct = 0; ct < 2; ++ct)
#pragma unroll
                for (int r = 0; r < 4; ++r)
                    hb[(rt * 16 + q * 4 + r) * HS + c0 + ct * 16 + l15] = stg[rt][ct][r];
    }
    __syncthreads();
    fvec4 a3[4][4];
#pragma unroll
    for (int rt = 0; rt < 4; ++rt)
#pragma unroll
        for (int ct = 0; ct < 4; ++ct) a3[rt][ct] = fz;
#pragma unroll 1
    for (int kc = 0; kc < 8; ++kc) {
        const int k0 = kc * 32 + q * 8;
        short8 a8[4];
#pragma unroll
        for (int rt = 0; rt < 4; ++rt) a8[rt] = ld8(hb + (rt * 16 + l15) * HS + k0);
#pragma unroll
        for (int ct = 0; ct < 4; ++ct) {
            short8 b8 = ld8(Winitb + (((w * 4 + ct) * 8 + kc) * 64 + lane) * 8);
#pragma unroll
            for (int rt = 0; rt < 4; ++rt) a3[rt][ct] = mfma16(a8[rt], b8, a3[rt][ct]);
        }
    }
    const int c0i = w * 64;
#pragma unroll
    for (int ct = 0; ct < 4; ++ct) {
        const int j = c0i + ct * 16 + l15;
        const float bz = binit[j];
        const int half = j >> 8, cc = j & 255;
#pragma unroll
        for (int rt = 0; rt < 4; ++rt)
#pragma unroll
            for (int r = 0; r < 4; ++r) {
                const int i = rows0 + rt * 16 + q * 4 + r;
                const unsigned short v = f2bf(a3[rt][ct][r] + bz);
                if (i < 16384) h0g[(2 * i + half) * 256 + cc] = v;
                else           h1g[(2 * (i - 16384) + half) * 256 + cc] = v;
            }
    }
}

// ---------------- fused 10-step rollout (v6) -------------------------------
// 512 blocks x 512 threads (8 waves); wave = 64 rows (rt=4) x 32 cols (ct=2).
// All state in LDS; packed coalesced weight loads; no spills.
__global__ __launch_bounds__(512, 2) void k_roll(
    const unsigned short* __restrict__ h0g, const unsigned short* __restrict__ h1g,
    const unsigned short* __restrict__ Wih0b, const unsigned short* __restrict__ Whh0b,
    const unsigned short* __restrict__ Wih1b, const unsigned short* __restrict__ Whh1b,
    const unsigned short* __restrict__ Wab,
    const float* __restrict__ bih0, const float* __restrict__ bhh0,
    const float* __restrict__ bih1, const float* __restrict__ bhh1,
    const float* __restrict__ ba, float* __restrict__ out)
{
    __shared__ unsigned short h0s[64 * HS];
    __shared__ unsigned short h1s[64 * HS];
    __shared__ unsigned short avs[64 * 8];
    __shared__ float ldsb[2048];    // [cell0: br,bz,bi,bh][cell1: same] x 256
    const int tid = threadIdx.x, lane = tid & 63, w = tid >> 6;
    const int l15 = lane & 15, q = lane >> 4;
    const int rows0 = blockIdx.x * 64;
    const int cb = w * 32;
    const fvec4 fz = {0.f, 0.f, 0.f, 0.f};
    const short8 z8 = {0,0,0,0,0,0,0,0};

    // ---- h state global -> LDS; biases -> LDS ----
    for (int it = tid; it < 64 * 32; it += 512) {
        const int row = it >> 5, g = (it & 31) * 8;
        *reinterpret_cast<short8*>(h0s + row * HS + g) = ld8(h0g + (rows0 + row) * 256 + g);
        *reinterpret_cast<short8*>(h1s + row * HS + g) = ld8(h1g + (rows0 + row) * 256 + g);
    }
    if (tid < 256) {
        const int j = tid;
        ldsb[j]       = bih0[j] + bhh0[j];
        ldsb[256 + j] = bih0[256 + j] + bhh0[256 + j];
        ldsb[512 + j] = bih0[512 + j];
        ldsb[768 + j] = bhh0[512 + j];
    } else {
        const int j = tid - 256;
        ldsb[1024 + j] = bih1[j] + bhh1[j];
        ldsb[1280 + j] = bih1[256 + j] + bhh1[256 + j];
        ldsb[1536 + j] = bih1[512 + j];
        ldsb[1792 + j] = bhh1[512 + j];
    }
    const float bav = ba[l15 & 7];
    __syncthreads();

    for (int t = 0; t < 10; ++t) {
        // ================= GRU cell 0 =================
        {
            fvec4 aR[4][2], aZ[4][2], aNi[4][2], aNh[4][2];
#pragma unroll
            for (int rt = 0; rt < 4; ++rt)
#pragma unroll
                for (int ct = 0; ct < 2; ++ct) { aR[rt][ct]=fz; aZ[rt][ct]=fz; aNi[rt][ct]=fz; aNh[rt][ct]=fz; }
#pragma unroll 2
            for (int kc = 0; kc < 8; ++kc) {
                const int k0 = kc * 32 + q * 8;
                short8 wr[2], wz[2], wn[2];
#pragma unroll
                for (int ct = 0; ct < 2; ++ct) {
                    const unsigned short* wp =
                        Whh0b + ((((w * 2 + ct) * 8 + kc) * 64 + lane) * 8);
                    wr[ct] = ld8(wp);
                    wz[ct] = ld8(wp + 65536);
                    wn[ct] = ld8(wp + 131072);
                }
                short8 ah[4];
#pragma unroll
                for (int rt = 0; rt < 4; ++rt)
                    ah[rt] = ld8(h0s + (rt * 16 + l15) * HS + k0);
#pragma unroll
                for (int ct = 0; ct < 2; ++ct)
#pragma unroll
                    for (int rt = 0; rt < 4; ++rt) {
                        aR[rt][ct]  = mfma16(ah[rt], wr[ct], aR[rt][ct]);
                        aZ[rt][ct]  = mfma16(ah[rt], wz[ct], aZ[rt][ct]);
                        aNh[rt][ct] = mfma16(ah[rt], wn[ct], aNh[rt][ct]);
                    }
            }
            if (t > 0) {       // action GEMM K=8 in one K=32 chunk (quads 1-3 -> 0)
                short8 av[4];
#pragma unroll
                for (int rt = 0; rt < 4; ++rt) {
                    short8 v = ld8(avs + (rt * 16 + l15) * 8);
                    av[rt] = (q == 0) ? v : z8;
                }
#pragma unroll
                for (int ct = 0; ct < 2; ++ct) {
                    const unsigned short* wp = Wih0b + (cb + ct * 16 + l15) * 8;
                    short8 wr = ld8(wp);
                    short8 wz = ld8(wp + 2048);
                    short8 wn = ld8(wp + 4096);
#pragma unroll
                    for (int rt = 0; rt < 4; ++rt) {
                        aR[rt][ct]  = mfma16(av[rt], wr, aR[rt][ct]);
                        aZ[rt][ct]  = mfma16(av[rt], wz, aZ[rt][ct]);
                        aNi[rt][ct] = mfma16(av[rt], wn, aNi[rt][ct]);
                    }
                }
            }
            // epilogue: hnew (fp32) stashed into dead aR regs
#pragma unroll
            for (int ct = 0; ct < 2; ++ct) {
                const int c = cb + ct * 16 + l15;
                const float br = ldsb[c], bz = ldsb[256 + c];
                const float bi = ldsb[512 + c], bh = ldsb[768 + c];
#pragma unroll
                for (int rt = 0; rt < 4; ++rt)
#pragma unroll
                    for (int r = 0; r < 4; ++r) {
                        const int row = rt * 16 + q * 4 + r;
                        const float hold = bf2f(h0s[row * HS + c]);
                        const float rr = sigm(aR[rt][ct][r] + br);
                        const float zz = sigm(aZ[rt][ct][r] + bz);
                        const float nn = tanh_f(aNi[rt][ct][r] + bi + rr * (aNh[rt][ct][r] + bh));
                        aR[rt][ct][r] = (1.f - zz) * nn + zz * hold;
                    }
            }
            __syncthreads();   // all reads of h0s done
#pragma unroll
            for (int ct = 0; ct < 2; ++ct) {
                const int c = cb + ct * 16 + l15;
#pragma unroll
                for (int rt = 0; rt < 4; ++rt)
#pragma unroll
                    for (int r = 0; r < 4; ++r)
                        h0s[(rt * 16 + q * 4 + r) * HS + c] = f2bf(aR[rt][ct][r]);
            }
        }
        __syncthreads();   // h0s = h0n
        // ================= GRU cell 1 =================
        {
            fvec4 aR[4][2], aZ[4][2], aNi[4][2], aNh[4][2];
#pragma unroll
            for (int rt = 0; rt < 4; ++rt)
#pragma unroll
                for (int ct = 0; ct < 2; ++ct) { aR[rt][ct]=fz; aZ[rt][ct]=fz; aNi[rt][ct]=fz; aNh[rt][ct]=fz; }
#pragma unroll 1
            for (int kc = 0; kc < 8; ++kc) {
                const int k0 = kc * 32 + q * 8;
                short8 wir[2], wiz[2], win[2], whr[2], whz[2], whn[2];
#pragma unroll
                for (int ct = 0; ct < 2; ++ct) {
                    const int fo = (((w * 2 + ct) * 8 + kc) * 64 + lane) * 8;
                    const unsigned short* wi = Wih1b + fo;
                    const unsigned short* wh = Whh1b + fo;
                    wir[ct] = ld8(wi);
                    whr[ct] = ld8(wh);
                    wiz[ct] = ld8(wi + 65536);
                    whz[ct] = ld8(wh + 65536);
                    win[ct] = ld8(wi + 131072);
                    whn[ct] = ld8(wh + 131072);
                }
                short8 ai[4], ah[4];
#pragma unroll
                for (int rt = 0; rt < 4; ++rt) {
                    const int rr = (rt * 16 + l15) * HS + k0;
                    ai[rt] = ld8(h0s + rr);
                    ah[rt] = ld8(h1s + rr);
                }
#pragma unroll
                for (int ct = 0; ct < 2; ++ct)
#pragma unroll
                    for (int rt = 0; rt < 4; ++rt) {
                        aR[rt][ct]  = mfma16(ai[rt], wir[ct], aR[rt][ct]);
                        aR[rt][ct]  = mfma16(ah[rt], whr[ct], aR[rt][ct]);
                        aZ[rt][ct]  = mfma16(ai[rt], wiz[ct], aZ[rt][ct]);
                        aZ[rt][ct]  = mfma16(ah[rt], whz[ct], aZ[rt][ct]);
                        aNi[rt][ct] = mfma16(ai[rt], win[ct], aNi[rt][ct]);
                        aNh[rt][ct] = mfma16(ah[rt], whn[ct], aNh[rt][ct]);
                    }
            }
#pragma unroll
            for (int ct = 0; ct < 2; ++ct) {
                const int c = cb + ct * 16 + l15;
                const float br = ldsb[1024 + c], bz = ldsb[1280 + c];
                const float bi = ldsb[1536 + c], bh = ldsb[1792 + c];
#pragma unroll
                for (int rt = 0; rt < 4; ++rt)
#pragma unroll
                    for (int r = 0; r < 4; ++r) {
                        const int row = rt * 16 + q * 4 + r;
                        const float hold = bf2f(h1s[row * HS + c]);
                        const float rr = sigm(aR[rt][ct][r] + br);
                        const float zz = sigm(aZ[rt][ct][r] + bz);
                        const float nn = tanh_f(aNi[rt][ct][r] + bi + rr * (aNh[rt][ct][r] + bh));
                        aR[rt][ct][r] = (1.f - zz) * nn + zz * hold;
                    }
            }
            __syncthreads();   // all reads of h1s done
#pragma unroll
            for (int ct = 0; ct < 2; ++ct) {
                const int c = cb + ct * 16 + l15;
#pragma unroll
                for (int rt = 0; rt < 4; ++rt)
#pragma unroll
                    for (int r = 0; r < 4; ++r)
                        h1s[(rt * 16 + q * 4 + r) * HS + c] = f2bf(aR[rt][ct][r]);
            }
        }
        __syncthreads();   // h1s = h1n
        // ================= logits + softmax -> a (waves 0-3: 16 rows each) ====
        if (w < 4) {
            fvec4 f = fz;
#pragma unroll 1
            for (int kc = 0; kc < 8; ++kc) {
                const int k0 = kc * 32 + q * 8;
                short8 a8 = ld8(h1s + (w * 16 + l15) * HS + k0);
                short8 b8 = ld8(Wab + (l15 & 7) * 256 + k0);   // cols 8-15 dup, ignored
                f = mfma16(a8, b8, f);
            }
#pragma unroll
            for (int r = 0; r < 4; ++r) {
                float s = f[r] + bav;
                float m = s;
                m = fmaxf(m, __shfl_xor(m, 1, 64));
                m = fmaxf(m, __shfl_xor(m, 2, 64));
                m = fmaxf(m, __shfl_xor(m, 4, 64));
                float e = __expf(s - m);
                float se = e;
                se += __shfl_xor(se, 1, 64);
                se += __shfl_xor(se, 2, 64);
                se += __shfl_xor(se, 4, 64);
                if (l15 < 8) {
                    const int lrow = w * 16 + q * 4 + r;
                    out[(rows0 + lrow) * 80 + t * 8 + l15] = s;
                    avs[lrow * 8 + l15] = f2bf(e * __builtin_amdgcn_rcpf(se));
                }
            }
        }
        __syncthreads();   // avs ready for next step
    }
}

// ---------------- host side -----------------------------------------------
extern "C" void kernel_launch(void* const* d_in, const int* in_sizes, int n_in,
                              void* d_out, int out_size, void* d_ws, size_t ws_size,
                              hipStream_t stream)
{
    const float* ini   = (const float*)d_in[0];
    const float* fin   = (const float*)d_in[1];
    /* d_in[2] = horizon (always 10) */
    const float* W1    = (const float*)d_in[3];
    const float* b1    = (const float*)d_in[4];
    const float* lng   = (const float*)d_in[5];
    const float* lnb   = (const float*)d_in[6];
    const float* W2    = (const float*)d_in[7];
    const float* b2    = (const float*)d_in[8];
    const float* Wih0  = (const float*)d_in[9];
    const float* Whh0  = (const float*)d_in[10];
    const float* bih0  = (const float*)d_in[11];
    const float* bhh0  = (const float*)d_in[12];
    const float* Wih1  = (const float*)d_in[13];
    const float* Whh1  = (const float*)d_in[14];
    const float* bih1  = (const float*)d_in[15];
    const float* bhh1  = (const float*)d_in[16];
    const float* Wa    = (const float*)d_in[17];
    const float* ba    = (const float*)d_in[18];
    const float* Winit = (const float*)d_in[19];
    const float* binit = (const float*)d_in[20];
    float* out = (float*)d_out;

    char* ws = (char*)d_ws;
    unsigned short* wb     = (unsigned short*)ws;
    unsigned short* W1b    = wb;
    unsigned short* W2b    = wb + 262144;
    unsigned short* Winitb = wb + 327680;
    unsigned short* Wih0b  = wb + 458752;
    unsigned short* Whh0b  = wb + 464896;
    unsigned short* Wih1b  = wb + 661504;
    unsigned short* Whh1b  = wb + 858112;
    unsigned short* Wab    = wb + 1054720;
    unsigned short* h0g = (unsigned short*)(ws + 2113536);
    unsigned short* h1g = (unsigned short*)(ws + 18890752);

    k_prep<<<dim3(4128), dim3(256), 0, stream>>>(W1, W2, Winit, Wih0, Whh0, Wih1, Whh1, Wa, wb);
    k_encode<<<dim3(512), dim3(512), 0, stream>>>(ini, fin, W1b, b1, lng, lnb, W2b, b2,
                                                  Winitb, binit, h0g, h1g);
    k_roll<<<dim3(512), dim3(512), 0, stream>>>(h0g, h1g, Wih0b, Whh0b, Wih1b, Whh1b, Wab,
                                                bih0, bhh0, bih1, bhh1, ba, out);
}

// Round 7
// 707.814 us; speedup vs baseline: 6.6846x; 1.2454x over previous
//
#include <hip/hip_runtime.h>

// InverseTransitionModel, B=32768, H=256, 10 GRU steps.
// v7 = v6 (packed coalesced weights, register-budgeted) +
//   k_roll: LDS double-buffered h0/h1 (5 -> 3 barriers/step), biases folded
//           into MFMA accumulator init (epilogue shorter), no reg stash.
//   k_encode: fc1 input staged via LDS (coalesced 16B/thread loads) instead
//             of per-lane scattered 512B-strided fp32 reads.

#define HS 264   // LDS row stride in shorts (16B-aligned rows)

typedef __attribute__((ext_vector_type(8))) short short8;
typedef __attribute__((ext_vector_type(4))) float fvec4;

__device__ __forceinline__ float bf2f(unsigned short u) {
    union { unsigned int u; float f; } x; x.u = ((unsigned int)u) << 16; return x.f;
}
__device__ __forceinline__ unsigned short f2bf(float f) {
    union { float f; unsigned int u; } x; x.f = f;
    unsigned int r = x.u + 0x7fffu + ((x.u >> 16) & 1u);   // RNE
    return (unsigned short)(r >> 16);
}
__device__ __forceinline__ float sigm(float x)   { return __builtin_amdgcn_rcpf(1.f + __expf(-x)); }
__device__ __forceinline__ float tanh_f(float x) { return 2.f * __builtin_amdgcn_rcpf(1.f + __expf(-2.f * x)) - 1.f; }

__device__ __forceinline__ short8 ld8(const unsigned short* p) {
    return *reinterpret_cast<const short8*>(p);
}
__device__ __forceinline__ fvec4 mfma16(short8 a, short8 b, fvec4 c) {
    return __builtin_amdgcn_mfma_f32_16x16x32_bf16(a, b, c, 0, 0, 0);
}
__device__ __forceinline__ fvec4 splat4(float v) {
    fvec4 r = {v, v, v, v}; return r;
}

// fragment-pack offset: element (n,k) of an NxK matrix -> packed index.
// tile (n>>4, k>>5) holds 512 elems, lane-major: lane = ((k>>3)&3)*16 + (n&15),
// j = k&7. Lane l's 8 elems contiguous -> ld8 at base + lane*8 coalesces.
__device__ __forceinline__ int packoff(int e, int K) {
    const int n = e / K, k = e % K;
    return (((n >> 4) * (K >> 5) + (k >> 5)) << 9)
         + (((((k >> 3) & 3) << 4) | (n & 15)) << 3) + (k & 7);
}

// ---------------- weight cast fp32 -> bf16 + fragment packing ----------------
// ws short layout: W1[262144] W2[65536] Winit[131072] Wih0[6144 plain]
//                  Whh0[196608] Wih1[196608] Whh1[196608] Wa[2048 plain]
__global__ __launch_bounds__(256) void k_prep(
    const float* __restrict__ W1, const float* __restrict__ W2,
    const float* __restrict__ Winit, const float* __restrict__ Wih0,
    const float* __restrict__ Whh0, const float* __restrict__ Wih1,
    const float* __restrict__ Whh1, const float* __restrict__ Wa,
    unsigned short* __restrict__ wb)
{
    int i = blockIdx.x * 256 + threadIdx.x;
    if (i >= 1056768) return;
    float v; int dst;
    if (i < 262144) {
        v = W1[i];                dst = packoff(i, 1024);
    } else if (i < 327680) {
        int e = i - 262144;  v = W2[e];    dst = 262144 + packoff(e, 256);
    } else if (i < 458752) {
        int e = i - 327680;  v = Winit[e]; dst = 327680 + packoff(e, 256);
    } else if (i < 464896) {
        v = Wih0[i - 458752];     dst = i;
    } else if (i < 661504) {
        int e = i - 464896;  v = Whh0[e];  dst = 464896 + packoff(e, 256);
    } else if (i < 858112) {
        int e = i - 661504;  v = Wih1[e];  dst = 661504 + packoff(e, 256);
    } else if (i < 1054720) {
        int e = i - 858112;  v = Whh1[e];  dst = 858112 + packoff(e, 256);
    } else {
        v = Wa[i - 1054720];      dst = i;
    }
    wb[dst] = f2bf(v);
}

// ---------------- encoder: fc1 -> LN -> ReLU -> fc2 -> ReLU -> init -----------
// block = 64 rows, 8 waves; wave w -> cols [w*32, w*32+32).
// fc1 input staged via LDS (double-buffered, coalesced 16B/thread loads).
__global__ __launch_bounds__(512, 2) void k_encode(
    const float* __restrict__ ini, const float* __restrict__ fin,
    const unsigned short* __restrict__ W1b, const float* __restrict__ b1,
    const float* __restrict__ lng, const float* __restrict__ lnb,
    const unsigned short* __restrict__ W2b, const float* __restrict__ b2,
    const unsigned short* __restrict__ Winitb, const float* __restrict__ binit,
    unsigned short* __restrict__ h0g, unsigned short* __restrict__ h1g)
{
    __shared__ unsigned short hb[64 * HS];
    __shared__ unsigned short at[2][64 * 40];   // fc1 A-tiles, pad-40 stride
    __shared__ float ps[64][8][2];
    __shared__ float st[64][2];
    const int tid = threadIdx.x, lane = tid & 63, w = tid >> 6;
    const int l15 = lane & 15, q = lane >> 4;
    const int rows0 = blockIdx.x * 64;
    const int c0 = w * 32;
    const fvec4 fz = {0.f, 0.f, 0.f, 0.f};

    // stage thread-mapping for fc1 A-tiles: 64 rows x 32 k fp32 per chunk
    const int srow = tid >> 3, sseg = (tid & 7) * 4;

    // ---- fc1: [64,1024] @ W1^T (staged A) ----
    fvec4 acc[4][2];
#pragma unroll
    for (int rt = 0; rt < 4; ++rt) { acc[rt][0] = fz; acc[rt][1] = fz; }
    {
        // stage chunk 0
        const float* src0 = ini + (rows0 + srow) * 512 + sseg;
        fvec4 v = *reinterpret_cast<const fvec4*>(src0);
        union { unsigned short s[4]; unsigned long long u; } p;
        p.s[0] = f2bf(v[0]); p.s[1] = f2bf(v[1]); p.s[2] = f2bf(v[2]); p.s[3] = f2bf(v[3]);
        *reinterpret_cast<unsigned long long*>(&at[0][srow * 40 + sseg]) = p.u;
    }
    __syncthreads();
#pragma unroll 1
    for (int kc = 0; kc < 32; ++kc) {
        const int buf = kc & 1;
        if (kc < 31) {   // stage chunk kc+1 into other buffer
            const int k0 = (kc + 1) * 32 + sseg;
            const float* src = (k0 < 512) ? (ini + (rows0 + srow) * 512 + k0)
                                          : (fin + (rows0 + srow) * 512 + (k0 - 512));
            fvec4 v = *reinterpret_cast<const fvec4*>(src);
            union { unsigned short s[4]; unsigned long long u; } p;
            p.s[0] = f2bf(v[0]); p.s[1] = f2bf(v[1]); p.s[2] = f2bf(v[2]); p.s[3] = f2bf(v[3]);
            *reinterpret_cast<unsigned long long*>(&at[buf ^ 1][srow * 40 + sseg]) = p.u;
        }
        short8 b8a = ld8(W1b + (((w * 2 + 0) * 32 + kc) * 64 + lane) * 8);
        short8 b8b = ld8(W1b + (((w * 2 + 1) * 32 + kc) * 64 + lane) * 8);
        short8 a8[4];
#pragma unroll
        for (int rt = 0; rt < 4; ++rt)
            a8[rt] = ld8(&at[buf][(rt * 16 + l15) * 40 + q * 8]);
#pragma unroll
        for (int rt = 0; rt < 4; ++rt) {
            acc[rt][0] = mfma16(a8[rt], b8a, acc[rt][0]);
            acc[rt][1] = mfma16(a8[rt], b8b, acc[rt][1]);
        }
        __syncthreads();
    }
    // ---- bias + LN stats ----
    float bv[2] = { b1[c0 + l15], b1[c0 + 16 + l15] };
#pragma unroll
    for (int rt = 0; rt < 4; ++rt)
#pragma unroll
        for (int r = 0; r < 4; ++r) {
            float s = 0.f, s2 = 0.f;
#pragma unroll
            for (int ct = 0; ct < 2; ++ct) {
                float v = acc[rt][ct][r] + bv[ct];
                acc[rt][ct][r] = v;
                s += v; s2 += v * v;
            }
#pragma unroll
            for (int off = 1; off < 16; off <<= 1) {
                s  += __shfl_xor(s,  off, 64);
                s2 += __shfl_xor(s2, off, 64);
            }
            if (l15 == 0) {
                int row = rt * 16 + q * 4 + r;
                ps[row][w][0] = s; ps[row][w][1] = s2;
            }
        }
    __syncthreads();
    if (tid < 64) {
        float s = 0.f, s2 = 0.f;
#pragma unroll
        for (int j = 0; j < 8; ++j) { s += ps[tid][j][0]; s2 += ps[tid][j][1]; }
        float mu = s * (1.f / 256.f);
        float var = s2 * (1.f / 256.f) - mu * mu;
        st[tid][0] = mu; st[tid][1] = rsqrtf(var + 1e-5f);
    }
    __syncthreads();
    {
        float gv[2]  = { lng[c0 + l15], lng[c0 + 16 + l15] };
        float bbv[2] = { lnb[c0 + l15], lnb[c0 + 16 + l15] };
#pragma unroll
        for (int rt = 0; rt < 4; ++rt)
#pragma unroll
            for (int ct = 0; ct < 2; ++ct)
#pragma unroll
                for (int r = 0; r < 4; ++r) {
                    int row = rt * 16 + q * 4 + r;
                    float v = (acc[rt][ct][r] - st[row][0]) * st[row][1] * gv[ct] + bbv[ct];
                    v = fmaxf(v, 0.f);
                    hb[row * HS + c0 + ct * 16 + l15] = f2bf(v);
                }
    }
    __syncthreads();
    // ---- fc2: relu(hb @ W2^T + b2), in-place on hb ----
    fvec4 acc2[4][2];
#pragma unroll
    for (int rt = 0; rt < 4; ++rt) { acc2[rt][0] = fz; acc2[rt][1] = fz; }
#pragma unroll 2
    for (int kc = 0; kc < 8; ++kc) {
        const int k0 = kc * 32 + q * 8;
        short8 a8[4];
#pragma unroll
        for (int rt = 0; rt < 4; ++rt) a8[rt] = ld8(hb + (rt * 16 + l15) * HS + k0);
#pragma unroll
        for (int ct = 0; ct < 2; ++ct) {
            short8 b8 = ld8(W2b + (((w * 2 + ct) * 8 + kc) * 64 + lane) * 8);
#pragma unroll
            for (int rt = 0; rt < 4; ++rt) acc2[rt][ct] = mfma16(a8[rt], b8, acc2[rt][ct]);
        }
    }
    {
        float b2v[2] = { b2[c0 + l15], b2[c0 + 16 + l15] };
        unsigned short stg[4][2][4];
#pragma unroll
        for (int rt = 0; rt < 4; ++rt)
#pragma unroll
            for (int ct = 0; ct < 2; ++ct)
#pragma unroll
                for (int r = 0; r < 4; ++r)
                    stg[rt][ct][r] = f2bf(fmaxf(acc2[rt][ct][r] + b2v[ct], 0.f));
        __syncthreads();
#pragma unroll
        for (int rt = 0; rt < 4; ++rt)
#pragma unroll
            for (int ct = 0; ct < 2; ++ct)
#pragma unroll
                for (int r = 0; r < 4; ++r)
                    hb[(rt * 16 + q * 4 + r) * HS + c0 + ct * 16 + l15] = stg[rt][ct][r];
    }
    __syncthreads();
    // ---- init: hb @ Winit^T + binit -> h0g/h1g (torch view interleave) ----
    fvec4 a3[4][4];
#pragma unroll
    for (int rt = 0; rt < 4; ++rt)
#pragma unroll
        for (int ct = 0; ct < 4; ++ct) a3[rt][ct] = fz;
#pragma unroll 1
    for (int kc = 0; kc < 8; ++kc) {
        const int k0 = kc * 32 + q * 8;
        short8 a8[4];
#pragma unroll
        for (int rt = 0; rt < 4; ++rt) a8[rt] = ld8(hb + (rt * 16 + l15) * HS + k0);
#pragma unroll
        for (int ct = 0; ct < 4; ++ct) {
            short8 b8 = ld8(Winitb + (((w * 4 + ct) * 8 + kc) * 64 + lane) * 8);
#pragma unroll
            for (int rt = 0; rt < 4; ++rt) a3[rt][ct] = mfma16(a8[rt], b8, a3[rt][ct]);
        }
    }
    const int c0i = w * 64;
#pragma unroll
    for (int ct = 0; ct < 4; ++ct) {
        const int j = c0i + ct * 16 + l15;
        const float bz = binit[j];
        const int half = j >> 8, cc = j & 255;
#pragma unroll
        for (int rt = 0; rt < 4; ++rt)
#pragma unroll
            for (int r = 0; r < 4; ++r) {
                const int i = rows0 + rt * 16 + q * 4 + r;
                const unsigned short v = f2bf(a3[rt][ct][r] + bz);
                if (i < 16384) h0g[(2 * i + half) * 256 + cc] = v;
                else           h1g[(2 * (i - 16384) + half) * 256 + cc] = v;
            }
    }
}

// ---------------- fused 10-step rollout (v7) -------------------------------
// 512 blocks x 512 threads (8 waves); wave = 64 rows (rt=4) x 32 cols (ct=2).
// Double-buffered h0/h1 in LDS -> 3 barriers/step; biases folded into
// accumulator init; packed coalesced weight loads; no spills.
__global__ __launch_bounds__(512, 2) void k_roll(
    const unsigned short* __restrict__ h0g, const unsigned short* __restrict__ h1g,
    const unsigned short* __restrict__ Wih0b, const unsigned short* __restrict__ Whh0b,
    const unsigned short* __restrict__ Wih1b, const unsigned short* __restrict__ Whh1b,
    const unsigned short* __restrict__ Wab,
    const float* __restrict__ bih0, const float* __restrict__ bhh0,
    const float* __restrict__ bih1, const float* __restrict__ bhh1,
    const float* __restrict__ ba, float* __restrict__ out)
{
    __shared__ unsigned short h0sb[2][64 * HS];
    __shared__ unsigned short h1sb[2][64 * HS];
    __shared__ unsigned short avs[64 * 8];
    __shared__ float ldsb[2048];    // [cell0: br,bz,bi,bh][cell1: same] x 256
    const int tid = threadIdx.x, lane = tid & 63, w = tid >> 6;
    const int l15 = lane & 15, q = lane >> 4;
    const int rows0 = blockIdx.x * 64;
    const int cb = w * 32;
    const fvec4 fz = {0.f, 0.f, 0.f, 0.f};
    const short8 z8 = {0,0,0,0,0,0,0,0};

    // ---- h state global -> LDS buffer 0; biases -> LDS ----
    for (int it = tid; it < 64 * 32; it += 512) {
        const int row = it >> 5, g = (it & 31) * 8;
        *reinterpret_cast<short8*>(&h0sb[0][row * HS + g]) = ld8(h0g + (rows0 + row) * 256 + g);
        *reinterpret_cast<short8*>(&h1sb[0][row * HS + g]) = ld8(h1g + (rows0 + row) * 256 + g);
    }
    if (tid < 256) {
        const int j = tid;
        ldsb[j]       = bih0[j] + bhh0[j];
        ldsb[256 + j] = bih0[256 + j] + bhh0[256 + j];
        ldsb[512 + j] = bih0[512 + j];
        ldsb[768 + j] = bhh0[512 + j];
    } else {
        const int j = tid - 256;
        ldsb[1024 + j] = bih1[j] + bhh1[j];
        ldsb[1280 + j] = bih1[256 + j] + bhh1[256 + j];
        ldsb[1536 + j] = bih1[512 + j];
        ldsb[1792 + j] = bhh1[512 + j];
    }
    const float bav = ba[l15 & 7];
    __syncthreads();

    for (int t = 0; t < 10; ++t) {
        const int cur = t & 1, nxt = cur ^ 1;
        const unsigned short* h0c = h0sb[cur];
        unsigned short*       h0n = h0sb[nxt];
        const unsigned short* h1c = h1sb[cur];
        unsigned short*       h1n = h1sb[nxt];
        // ================= GRU cell 0: read h0c/avs, write h0n ==============
        {
            fvec4 aR[4][2], aZ[4][2], aNi[4][2], aNh[4][2];
#pragma unroll
            for (int ct = 0; ct < 2; ++ct) {
                const int c = cb + ct * 16 + l15;
                const float vr = ldsb[c],       vz = ldsb[256 + c];
                const float vi = ldsb[512 + c], vh = ldsb[768 + c];
#pragma unroll
                for (int rt = 0; rt < 4; ++rt) {
                    aR[rt][ct]  = splat4(vr);
                    aZ[rt][ct]  = splat4(vz);
                    aNi[rt][ct] = splat4(vi);
                    aNh[rt][ct] = splat4(vh);
                }
            }
#pragma unroll 2
            for (int kc = 0; kc < 8; ++kc) {
                const int k0 = kc * 32 + q * 8;
                short8 wr[2], wz[2], wn[2];
#pragma unroll
                for (int ct = 0; ct < 2; ++ct) {
                    const unsigned short* wp =
                        Whh0b + ((((w * 2 + ct) * 8 + kc) * 64 + lane) * 8);
                    wr[ct] = ld8(wp);
                    wz[ct] = ld8(wp + 65536);
                    wn[ct] = ld8(wp + 131072);
                }
                short8 ah[4];
#pragma unroll
                for (int rt = 0; rt < 4; ++rt)
                    ah[rt] = ld8(h0c + (rt * 16 + l15) * HS + k0);
#pragma unroll
                for (int ct = 0; ct < 2; ++ct)
#pragma unroll
                    for (int rt = 0; rt < 4; ++rt) {
                        aR[rt][ct]  = mfma16(ah[rt], wr[ct], aR[rt][ct]);
                        aZ[rt][ct]  = mfma16(ah[rt], wz[ct], aZ[rt][ct]);
                        aNh[rt][ct] = mfma16(ah[rt], wn[ct], aNh[rt][ct]);
                    }
            }
            if (t > 0) {       // action GEMM K=8 in one K=32 chunk (quads 1-3 -> 0)
                short8 av[4];
#pragma unroll
                for (int rt = 0; rt < 4; ++rt) {
                    short8 v = ld8(avs + (rt * 16 + l15) * 8);
                    av[rt] = (q == 0) ? v : z8;
                }
#pragma unroll
                for (int ct = 0; ct < 2; ++ct) {
                    const unsigned short* wp = Wih0b + (cb + ct * 16 + l15) * 8;
                    short8 wr = ld8(wp);
                    short8 wz = ld8(wp + 2048);
                    short8 wn = ld8(wp + 4096);
#pragma unroll
                    for (int rt = 0; rt < 4; ++rt) {
                        aR[rt][ct]  = mfma16(av[rt], wr, aR[rt][ct]);
                        aZ[rt][ct]  = mfma16(av[rt], wz, aZ[rt][ct]);
                        aNi[rt][ct] = mfma16(av[rt], wn, aNi[rt][ct]);
                    }
                }
            }
            // epilogue: write new h0 directly into the other buffer
#pragma unroll
            for (int ct = 0; ct < 2; ++ct) {
                const int c = cb + ct * 16 + l15;
#pragma unroll
                for (int rt = 0; rt < 4; ++rt)
#pragma unroll
                    for (int r = 0; r < 4; ++r) {
                        const int row = rt * 16 + q * 4 + r;
                        const float hold = bf2f(h0c[row * HS + c]);
                        const float rr = sigm(aR[rt][ct][r]);
                        const float zz = sigm(aZ[rt][ct][r]);
                        const float nn = tanh_f(aNi[rt][ct][r] + rr * aNh[rt][ct][r]);
                        h0n[row * HS + c] = f2bf((1.f - zz) * nn + zz * hold);
                    }
            }
        }
        __syncthreads();   // h0n visible
        // ================= GRU cell 1: read h0n/h1c, write h1n ==============
        {
            fvec4 aR[4][2], aZ[4][2], aNi[4][2], aNh[4][2];
#pragma unroll
            for (int ct = 0; ct < 2; ++ct) {
                const int c = cb + ct * 16 + l15;
                const float vr = ldsb[1024 + c], vz = ldsb[1280 + c];
                const float vi = ldsb[1536 + c], vh = ldsb[1792 + c];
#pragma unroll
                for (int rt = 0; rt < 4; ++rt) {
                    aR[rt][ct]  = splat4(vr);
                    aZ[rt][ct]  = splat4(vz);
                    aNi[rt][ct] = splat4(vi);
                    aNh[rt][ct] = splat4(vh);
                }
            }
#pragma unroll 1
            for (int kc = 0; kc < 8; ++kc) {
                const int k0 = kc * 32 + q * 8;
                short8 wir[2], wiz[2], win[2], whr[2], whz[2], whn[2];
#pragma unroll
                for (int ct = 0; ct < 2; ++ct) {
                    const int fo = (((w * 2 + ct) * 8 + kc) * 64 + lane) * 8;
                    const unsigned short* wi = Wih1b + fo;
                    const unsigned short* wh = Whh1b + fo;
                    wir[ct] = ld8(wi);
                    whr[ct] = ld8(wh);
                    wiz[ct] = ld8(wi + 65536);
                    whz[ct] = ld8(wh + 65536);
                    win[ct] = ld8(wi + 131072);
                    whn[ct] = ld8(wh + 131072);
                }
                short8 ai[4], ah[4];
#pragma unroll
                for (int rt = 0; rt < 4; ++rt) {
                    const int rr = (rt * 16 + l15) * HS + k0;
                    ai[rt] = ld8(h0n + rr);
                    ah[rt] = ld8(h1c + rr);
                }
#pragma unroll
                for (int ct = 0; ct < 2; ++ct)
#pragma unroll
                    for (int rt = 0; rt < 4; ++rt) {
                        aR[rt][ct]  = mfma16(ai[rt], wir[ct], aR[rt][ct]);
                        aR[rt][ct]  = mfma16(ah[rt], whr[ct], aR[rt][ct]);
                        aZ[rt][ct]  = mfma16(ai[rt], wiz[ct], aZ[rt][ct]);
                        aZ[rt][ct]  = mfma16(ah[rt], whz[ct], aZ[rt][ct]);
                        aNi[rt][ct] = mfma16(ai[rt], win[ct], aNi[rt][ct]);
                        aNh[rt][ct] = mfma16(ah[rt], whn[ct], aNh[rt][ct]);
                    }
            }
#pragma unroll
            for (int ct = 0; ct < 2; ++ct) {
                const int c = cb + ct * 16 + l15;
#pragma unroll
                for (int rt = 0; rt < 4; ++rt)
#pragma unroll
                    for (int r = 0; r < 4; ++r) {
                        const int row = rt * 16 + q * 4 + r;
                        const float hold = bf2f(h1c[row * HS + c]);
                        const float rr = sigm(aR[rt][ct][r]);
                        const float zz = sigm(aZ[rt][ct][r]);
                        const float nn = tanh_f(aNi[rt][ct][r] + rr * aNh[rt][ct][r]);
                        h1n[row * HS + c] = f2bf((1.f - zz) * nn + zz * hold);
                    }
            }
        }
        __syncthreads();   // h1n visible
        // ================= logits + softmax -> a (waves 0-3: 16 rows each) ====
        if (w < 4) {
            fvec4 f = fz;
#pragma unroll 1
            for (int kc = 0; kc < 8; ++kc) {
                const int k0 = kc * 32 + q * 8;
                short8 a8 = ld8(h1n + (w * 16 + l15) * HS + k0);
                short8 b8 = ld8(Wab + (l15 & 7) * 256 + k0);   // cols 8-15 dup, ignored
                f = mfma16(a8, b8, f);
            }
#pragma unroll
            for (int r = 0; r < 4; ++r) {
                float s = f[r] + bav;
                float m = s;
                m = fmaxf(m, __shfl_xor(m, 1, 64));
                m = fmaxf(m, __shfl_xor(m, 2, 64));
                m = fmaxf(m, __shfl_xor(m, 4, 64));
                float e = __expf(s - m);
                float se = e;
                se += __shfl_xor(se, 1, 64);
                se += __shfl_xor(se, 2, 64);
                se += __shfl_xor(se, 4, 64);
                if (l15 < 8) {
                    const int lrow = w * 16 + q * 4 + r;
                    out[(rows0 + lrow) * 80 + t * 8 + l15] = s;
                    avs[lrow * 8 + l15] = f2bf(e * __builtin_amdgcn_rcpf(se));
                }
            }
        }
        __syncthreads();   // avs ready for next step
    }
}

// ---------------- host side -----------------------------------------------
extern "C" void kernel_launch(void* const* d_in, const int* in_sizes, int n_in,
                              void* d_out, int out_size, void* d_ws, size_t ws_size,
                              hipStream_t stream)
{
    const float* ini   = (const float*)d_in[0];
    const float* fin   = (const float*)d_in[1];
    /* d_in[2] = horizon (always 10) */
    const float* W1    = (const float*)d_in[3];
    const float* b1    = (const float*)d_in[4];
    const float* lng   = (const float*)d_in[5];
    const float* lnb   = (const float*)d_in[6];
    const float* W2    = (const float*)d_in[7];
    const float* b2    = (const float*)d_in[8];
    const float* Wih0  = (const float*)d_in[9];
    const float* Whh0  = (const float*)d_in[10];
    const float* bih0  = (const float*)d_in[11];
    const float* bhh0  = (const float*)d_in[12];
    const float* Wih1  = (const float*)d_in[13];
    const float* Whh1  = (const float*)d_in[14];
    const float* bih1  = (const float*)d_in[15];
    const float* bhh1  = (const float*)d_in[16];
    const float* Wa    = (const float*)d_in[17];
    const float* ba    = (const float*)d_in[18];
    const float* Winit = (const float*)d_in[19];
    const float* binit = (const float*)d_in[20];
    float* out = (float*)d_out;

    char* ws = (char*)d_ws;
    unsigned short* wb     = (unsigned short*)ws;
    unsigned short* W1b    = wb;
    unsigned short* W2b    = wb + 262144;
    unsigned short* Winitb = wb + 327680;
    unsigned short* Wih0b  = wb + 458752;
    unsigned short* Whh0b  = wb + 464896;
    unsigned short* Wih1b  = wb + 661504;
    unsigned short* Whh1b  = wb + 858112;
    unsigned short* Wab    = wb + 1054720;
    unsigned short* h0g = (unsigned short*)(ws + 2113536);
    unsigned short* h1g = (unsigned short*)(ws + 18890752);

    k_prep<<<dim3(4128), dim3(256), 0, stream>>>(W1, W2, Winit, Wih0, Whh0, Wih1, Whh1, Wa, wb);
    k_encode<<<dim3(512), dim3(512), 0, stream>>>(ini, fin, W1b, b1, lng, lnb, W2b, b2,
                                                  Winitb, binit, h0g, h1g);
    k_roll<<<dim3(512), dim3(512), 0, stream>>>(h0g, h1g, Wih0b, Whh0b, Wih1b, Whh1b, Wab,
                                                bih0, bhh0, bih1, bhh1, ba, out);
}